// Round 2
// baseline (662.117 us; speedup 1.0000x reference)
//
#include <hip/hip_runtime.h>
#include <math.h>

// Problem constants (setup_inputs is fixed)
#define BB   4
#define HH   128
#define WW2  128
#define NN   (HH*WW2)     // 16384
#define CC   256
#define NH   8
#define HID  768
#define EPSF 1e-6f
#define SCALE 0.17677669529663687f   // 32^-0.5

typedef __attribute__((ext_vector_type(8))) short s8v;   // 8 bf16 (4 VGPRs) MFMA A/B frag
typedef __attribute__((ext_vector_type(4))) float f4v;   // MFMA C/D frag

// ---- bf16 helpers (raw ushort storage) ----
__device__ __forceinline__ float bf2f(ushort h) {
    union { unsigned u; float f; } x; x.u = ((unsigned)h) << 16; return x.f;
}
__device__ __forceinline__ ushort f2bf(float f) {
    union { float f; unsigned u; } x; x.f = f;
    unsigned r = (x.u + 0x7FFFu + ((x.u >> 16) & 1u)) >> 16;
    return (ushort)r;
}

typedef __attribute__((address_space(1))) unsigned gu32;
typedef __attribute__((address_space(3))) unsigned lu32;
__device__ __forceinline__ void gl_lds16(const void* g, void* l) {
    __builtin_amdgcn_global_load_lds((gu32*)g, (lu32*)l, 16, 0, 0);
}

// ---------------- LayerNorm -> bf16, 4 rows per block, vectorized ----------------
__global__ __launch_bounds__(256) void ln_bf16v(const float* __restrict__ in,
                                                const float* __restrict__ g,
                                                const float* __restrict__ bta,
                                                ushort* __restrict__ out) {
    int row  = blockIdx.x*4 + (threadIdx.x >> 6);
    int lane = threadIdx.x & 63;
    const float* p = in + (size_t)row*CC + lane*4;
    float4 v = *(const float4*)p;
    float s  = v.x + v.y + v.z + v.w;
    float s2 = v.x*v.x + v.y*v.y + v.z*v.z + v.w*v.w;
    #pragma unroll
    for (int off = 32; off >= 1; off >>= 1) {
        s  += __shfl_xor(s, off);
        s2 += __shfl_xor(s2, off);
    }
    float mean = s * (1.0f/CC);
    float var  = s2 * (1.0f/CC) - mean*mean;
    float r    = rsqrtf(var + EPSF);
    float4 gv = *(const float4*)&g[lane*4];
    float4 bv = *(const float4*)&bta[lane*4];
    ushort4 o;
    o.x = f2bf((v.x-mean)*r*gv.x + bv.x);
    o.y = f2bf((v.y-mean)*r*gv.y + bv.y);
    o.z = f2bf((v.z-mean)*r*gv.z + bv.z);
    o.w = f2bf((v.w-mean)*r*gv.w + bv.w);
    *(ushort4*)&out[(size_t)row*CC + lane*4] = o;
}

// ---------------- LDS-tiled weight transpose + bf16 cast: w[K][N] -> wt[N][K] ----------------
__global__ __launch_bounds__(256) void wtrans(const float* __restrict__ w,
                                              ushort* __restrict__ wt, int K, int N) {
    __shared__ float tile[32][33];
    int k0 = blockIdx.x*32, n0 = blockIdx.y*32;
    int c = threadIdx.x & 31, r8 = threadIdx.x >> 5;
    #pragma unroll
    for (int r = 0; r < 4; ++r) {
        int kk = r8 + r*8;
        tile[kk][c] = w[(size_t)(k0+kk)*N + n0 + c];
    }
    __syncthreads();
    #pragma unroll
    for (int r = 0; r < 4; ++r) {
        int nn = r8 + r*8;
        wt[(size_t)(n0+nn)*K + k0 + c] = f2bf(tile[c][nn]);
    }
}

// ---- proj_w[K=256][N=256] -> Bcat[b][n][256+k] (projT half of concatenated B), 4 copies ----
__global__ __launch_bounds__(256) void wtrans_proj(const float* __restrict__ w,
                                                   ushort* __restrict__ Bcat) {
    __shared__ float tile[32][33];
    int k0 = blockIdx.x*32, n0 = blockIdx.y*32;
    int c = threadIdx.x & 31, r8 = threadIdx.x >> 5;
    #pragma unroll
    for (int r = 0; r < 4; ++r) {
        int kk = r8 + r*8;
        tile[kk][c] = w[(size_t)(k0+kk)*CC + n0 + c];
    }
    __syncthreads();
    #pragma unroll
    for (int r = 0; r < 4; ++r) {
        int nn = r8 + r*8;
        ushort val = f2bf(tile[c][nn]);
        #pragma unroll
        for (int b = 0; b < BB; ++b)
            Bcat[((size_t)(b*256 + n0+nn))*512 + 256 + k0 + c] = val;
    }
}

// ---------------- bf16 MFMA GEMM: C[M,N] = A[M,K] @ Bt[N,K]^T + bias (+resid) ----------------
// 2-phase double-buffered K-loop (T3-minimum): stage tile k+1 before computing tile k.
// XCD-aware block swizzle (grids all divisible by 8).
// MODE 0: bf16 out, stride NDIM.  MODE 1: f32 out = acc+bias+resid, stride NDIM.
// MODE 2: qkv split writer: col<256 -> aq (stride 512); col<512 -> kbuf; else vbuf (stride 256).
template<int KDIM, int MODE>
__global__ __launch_bounds__(256) void mfma_gemm(const ushort* __restrict__ A,
                                                 const ushort* __restrict__ Bt,
                                                 const float* __restrict__ bias,
                                                 const float* __restrict__ resid,
                                                 void* __restrict__ Cout,
                                                 ushort* __restrict__ kbuf,
                                                 ushort* __restrict__ vbuf,
                                                 int NDIM) {
    __shared__ ushort lsA[2][128*32];
    __shared__ ushort lsB[2][128*32];
    int tid  = threadIdx.x;
    int lane = tid & 63;
    int w    = tid >> 6;
    int wm   = w >> 1, wn = w & 1;

    // XCD swizzle: contiguous chunk of linear block ids per XCD (nwg % 8 == 0)
    int nwg = gridDim.x * gridDim.y;
    int lin = blockIdx.y * gridDim.x + blockIdx.x;
    int swz = (lin & 7) * (nwg >> 3) + (lin >> 3);
    int bx  = swz % gridDim.x;
    int by  = swz / gridDim.x;

    size_t mBase = (size_t)by * 128;
    int    nBase = bx * 128;
    int lrow = lane & 15, lq = lane >> 4;

    const ushort* gA = A  + (mBase + w*32 + (lane>>2))*(size_t)KDIM + (lane&3)*8;
    const ushort* gB = Bt + ((size_t)(nBase + w*32 + (lane>>2)))*(size_t)KDIM + (lane&3)*8;
    ushort* lA0 = lsA[0] + w*1024;  ushort* lA1 = lsA[1] + w*1024;
    ushort* lB0 = lsB[0] + w*1024;  ushort* lB1 = lsB[1] + w*1024;

    f4v acc[4][4] = {};

    // prologue: stage K-tile 0 into buffer 0
    gl_lds16(gA,           lA0);
    gl_lds16(gA + 16*KDIM, lA0 + 512);
    gl_lds16(gB,           lB0);
    gl_lds16(gB + 16*KDIM, lB0 + 512);
    asm volatile("s_waitcnt vmcnt(0)" ::: "memory");
    __builtin_amdgcn_s_barrier();

    #pragma unroll
    for (int kk = 0; kk < KDIM/32; ++kk) {
        const int cur = kk & 1;
        if (kk + 1 < KDIM/32) {
            const int k1 = (kk+1)*32;
            ushort* nA = cur ? lA0 : lA1;
            ushort* nB = cur ? lB0 : lB1;
            gl_lds16(gA + k1,           nA);
            gl_lds16(gA + k1 + 16*KDIM, nA + 512);
            gl_lds16(gB + k1,           nB);
            gl_lds16(gB + k1 + 16*KDIM, nB + 512);
        }
        s8v af[4], bfr[4];
        #pragma unroll
        for (int i = 0; i < 4; ++i)
            af[i] = *(const s8v*)&lsA[cur][(wm*64 + i*16 + lrow)*32 + lq*8];
        #pragma unroll
        for (int j = 0; j < 4; ++j)
            bfr[j] = *(const s8v*)&lsB[cur][(wn*64 + j*16 + lrow)*32 + lq*8];
        #pragma unroll
        for (int i = 0; i < 4; ++i)
            #pragma unroll
            for (int j = 0; j < 4; ++j)
                acc[i][j] = __builtin_amdgcn_mfma_f32_16x16x32_bf16(af[i], bfr[j], acc[i][j], 0, 0, 0);
        // one drain+barrier per K-step: prefetch issued above has been covered
        // by ds_read+MFMA latency; also guarantees all waves' reads of buf[cur]
        // are done before it is overwritten next iteration.
        asm volatile("s_waitcnt vmcnt(0) lgkmcnt(0)" ::: "memory");
        __builtin_amdgcn_s_barrier();
    }

    int colBase = nBase + wn*64;
    #pragma unroll
    for (int j = 0; j < 4; ++j) {
        int col = colBase + j*16 + lrow;
        float bs = bias[col];
        #pragma unroll
        for (int i = 0; i < 4; ++i) {
            #pragma unroll
            for (int r = 0; r < 4; ++r) {
                size_t row = mBase + wm*64 + i*16 + lq*4 + r;
                float v = acc[i][j][r] + bs;
                if constexpr (MODE == 0) {
                    ((ushort*)Cout)[row*(size_t)NDIM + col] = f2bf(v);
                } else if constexpr (MODE == 1) {
                    size_t idx = row*(size_t)NDIM + col;
                    ((float*)Cout)[idx] = v + resid[idx];
                } else {
                    if (col < 256)      ((ushort*)Cout)[row*512 + col] = f2bf(v);
                    else if (col < 512) kbuf[row*256 + col - 256] = f2bf(v);
                    else                vbuf[row*256 + col - 512] = f2bf(v);
                }
            }
        }
    }
}

// ---- attention proj GEMM: A=aq[B*N,512] contiguous, B=Bcat per batch, K=512 ----
__global__ __launch_bounds__(256) void mfma_gemm_attn(const ushort* __restrict__ aq,
                                                      const ushort* __restrict__ Bcat,
                                                      const float* __restrict__ bias,
                                                      const float* __restrict__ resid,
                                                      float* __restrict__ Cout) {
    __shared__ ushort lsA[2][128*32];
    __shared__ ushort lsB[2][128*32];
    int tid  = threadIdx.x;
    int lane = tid & 63;
    int w    = tid >> 6;
    int wm   = w >> 1, wn = w & 1;
    int b = blockIdx.z;

    // XCD swizzle within the per-batch 2D grid (2*128 = 256 blocks, %8==0)
    int nwg = gridDim.x * gridDim.y;
    int lin = blockIdx.y * gridDim.x + blockIdx.x;
    int swz = (lin & 7) * (nwg >> 3) + (lin >> 3);
    int bx  = swz % gridDim.x;
    int by  = swz / gridDim.x;

    size_t mBase = (size_t)b*NN + (size_t)by * 128;
    int    nBase = bx * 128;
    int lrow = lane & 15, lq = lane >> 4;

    const ushort* gA = aq + (mBase + w*32 + (lane>>2))*512 + (lane&3)*8;
    const ushort* gB = Bcat + ((size_t)(b*256 + nBase + w*32 + (lane>>2)))*512 + (lane&3)*8;
    ushort* lA0 = lsA[0] + w*1024;  ushort* lA1 = lsA[1] + w*1024;
    ushort* lB0 = lsB[0] + w*1024;  ushort* lB1 = lsB[1] + w*1024;

    f4v acc[4][4] = {};

    gl_lds16(gA,          lA0);
    gl_lds16(gA + 16*512, lA0 + 512);
    gl_lds16(gB,          lB0);
    gl_lds16(gB + 16*512, lB0 + 512);
    asm volatile("s_waitcnt vmcnt(0)" ::: "memory");
    __builtin_amdgcn_s_barrier();

    #pragma unroll
    for (int kk = 0; kk < 512/32; ++kk) {
        const int cur = kk & 1;
        if (kk + 1 < 512/32) {
            const int k1 = (kk+1)*32;
            ushort* nA = cur ? lA0 : lA1;
            ushort* nB = cur ? lB0 : lB1;
            gl_lds16(gA + k1,          nA);
            gl_lds16(gA + k1 + 16*512, nA + 512);
            gl_lds16(gB + k1,          nB);
            gl_lds16(gB + k1 + 16*512, nB + 512);
        }
        s8v af[4], bfr[4];
        #pragma unroll
        for (int i = 0; i < 4; ++i)
            af[i] = *(const s8v*)&lsA[cur][(wm*64 + i*16 + lrow)*32 + lq*8];
        #pragma unroll
        for (int j = 0; j < 4; ++j)
            bfr[j] = *(const s8v*)&lsB[cur][(wn*64 + j*16 + lrow)*32 + lq*8];
        #pragma unroll
        for (int i = 0; i < 4; ++i)
            #pragma unroll
            for (int j = 0; j < 4; ++j)
                acc[i][j] = __builtin_amdgcn_mfma_f32_16x16x32_bf16(af[i], bfr[j], acc[i][j], 0, 0, 0);
        asm volatile("s_waitcnt vmcnt(0) lgkmcnt(0)" ::: "memory");
        __builtin_amdgcn_s_barrier();
    }

    int colBase = nBase + wn*64;
    #pragma unroll
    for (int j = 0; j < 4; ++j) {
        int col = colBase + j*16 + lrow;
        float bs = bias[col];
        #pragma unroll
        for (int i = 0; i < 4; ++i) {
            #pragma unroll
            for (int r = 0; r < 4; ++r) {
                size_t row = mBase + wm*64 + i*16 + lq*4 + r;
                size_t idx = row*(size_t)CC + col;
                Cout[idx] = acc[i][j][r] + bs + resid[idx];
            }
        }
    }
}

__global__ void zero_kernel(float* __restrict__ p, int nElems) {
    int i = blockIdx.x*256 + threadIdx.x;
    if (i < nElems) p[i] = 0.f;
}

// ------------- kv_raw[bh,kd,vd] += sum_n exp(k)*v ; ksum[bh,kd] += sum_n exp(k) -------------
// (no max-shift: |k| <~ 3 so exp() is safe in fp32; softmax is shift-invariant)
__global__ __launch_bounds__(256) void kv_accum(const ushort* __restrict__ kbuf,
                                                const ushort* __restrict__ vbuf,
                                                float* __restrict__ kv_raw,
                                                float* __restrict__ ksum) {
    int blk = blockIdx.x;
    int chunk = blk & 15;
    int bh = blk >> 4;
    int b = bh >> 3, hh = bh & 7;
    int tid = threadIdx.x;
    __shared__ float ke[32][36];
    __shared__ float vv[32][36];
    int tok = tid >> 3;           // 0..31 staging token
    int c4  = (tid & 7) * 4;      // staging channels
    int kd  = tid >> 3;           // compute: fixed k-channel
    int v0  = (tid & 7) * 4;      // compute: 4 v-channels
    float acc0=0.f, acc1=0.f, acc2=0.f, acc3=0.f, ks=0.f;
    for (int it = 0; it < 32; ++it) {
        int nb = chunk*1024 + it*32;
        size_t rowoff = ((size_t)b*NN + nb + tok)*256 + hh*32 + c4;
        ushort4 k4 = *(const ushort4*)&kbuf[rowoff];
        ushort4 v4 = *(const ushort4*)&vbuf[rowoff];
        float4 kf, vf;
        kf.x = expf(bf2f(k4.x)); kf.y = expf(bf2f(k4.y));
        kf.z = expf(bf2f(k4.z)); kf.w = expf(bf2f(k4.w));
        vf.x = bf2f(v4.x); vf.y = bf2f(v4.y); vf.z = bf2f(v4.z); vf.w = bf2f(v4.w);
        *(float4*)&ke[tok][c4] = kf;
        *(float4*)&vv[tok][c4] = vf;
        __syncthreads();
        #pragma unroll
        for (int tt = 0; tt < 32; ++tt) {
            float kval = ke[tt][kd];
            float4 vr = *(const float4*)&vv[tt][v0];
            ks   += kval;
            acc0 += kval*vr.x;
            acc1 += kval*vr.y;
            acc2 += kval*vr.z;
            acc3 += kval*vr.w;
        }
        __syncthreads();
    }
    float* dst = kv_raw + ((size_t)bh*32 + kd)*32 + v0;
    atomicAdd(dst+0, acc0); atomicAdd(dst+1, acc1);
    atomicAdd(dst+2, acc2); atomicAdd(dst+3, acc3);
    if (v0 == 0) atomicAdd(&ksum[bh*32 + kd], ks);
}

// ------------- fold: Bcat[b][j][h*32+kd] = SCALE * sum_vd (kv/ksum)[b,h,kd,vd] * proj_w[h*32+vd][j] -------------
__global__ __launch_bounds__(256) void kv_fold(const float* __restrict__ kv_raw,
                                               const float* __restrict__ ksum,
                                               const float* __restrict__ proj_w,
                                               ushort* __restrict__ Bcat) {
    int bh = blockIdx.x;           // 0..31
    int b = bh >> 3, hh = bh & 7;
    int tid = threadIdx.x;         // j = tid
    __shared__ float kvn[32][33];
    __shared__ float pw[32][256];
    {
        int kd = tid >> 3, v4 = (tid & 7) * 4;
        float inv = 1.0f / ksum[bh*32 + kd];
        const float* src = kv_raw + ((size_t)bh*32 + kd)*32 + v4;
        kvn[kd][v4+0] = src[0]*inv; kvn[kd][v4+1] = src[1]*inv;
        kvn[kd][v4+2] = src[2]*inv; kvn[kd][v4+3] = src[3]*inv;
    }
    for (int vd = 0; vd < 32; ++vd)
        pw[vd][tid] = proj_w[(size_t)(hh*32 + vd)*CC + tid];
    __syncthreads();
    ushort* dst = Bcat + ((size_t)(b*256 + tid))*512 + hh*32;
    for (int kd = 0; kd < 32; ++kd) {
        float acc = 0.f;
        #pragma unroll
        for (int vd = 0; vd < 32; ++vd) acc += kvn[kd][vd] * pw[vd][tid];
        dst[kd] = f2bf(SCALE * acc);
    }
}

// ------------- g = q * (dwconv3x3(v)+bias) -> aq[:,256:512]; 2 rows/block, ring -------------
// grid: (xq=4, yq=64, b=4), 256 threads = channels.
__global__ __launch_bounds__(256) void attn_gate(const ushort* __restrict__ vbuf,
                                                 const float* __restrict__ w,
                                                 const float* __restrict__ wb,
                                                 ushort* __restrict__ aq) {
    int xq = blockIdx.x, yq = blockIdx.y, b = blockIdx.z;
    int c = threadIdx.x;
    int y0 = yq*2;

    const float* wc = w + c*9;
    float w00=wc[0], w01=wc[1], w02=wc[2],
          w10=wc[3], w11=wc[4], w12=wc[5],
          w20=wc[6], w21=wc[7], w22=wc[8];
    float bw = wb[c];

    const ushort* vbase = vbuf + (size_t)b*NN*256 + c;
    auto ldv = [&](int yy, int xx) -> float {
        if ((unsigned)yy >= (unsigned)HH || (unsigned)xx >= (unsigned)WW2) return 0.f;
        return bf2f(vbase[((size_t)yy*WW2 + xx)*256]);
    };

    int x0 = xq*32;
    float rp[4], rc[4];
    #pragma unroll
    for (int r = 0; r < 4; ++r) {
        rp[r] = ldv(y0-1+r, x0-1);
        rc[r] = ldv(y0-1+r, x0);
    }

    #pragma unroll 4
    for (int i = 0; i < 32; ++i) {
        int x = x0 + i;
        float rn[4];
        #pragma unroll
        for (int r = 0; r < 4; ++r) rn[r] = ldv(y0-1+r, x+1);
        #pragma unroll
        for (int o = 0; o < 2; ++o) {
            float conv = bw + w00*rp[o] + w01*rc[o] + w02*rn[o]
                            + w10*rp[o+1] + w11*rc[o+1] + w12*rn[o+1]
                            + w20*rp[o+2] + w21*rc[o+2] + w22*rn[o+2];
            size_t bn = (size_t)b*NN + (size_t)(y0+o)*WW2 + x;
            float qc = bf2f(aq[bn*512 + c]);
            aq[bn*512 + 256 + c] = f2bf(qc*conv);
        }
        #pragma unroll
        for (int r = 0; r < 4; ++r) { rp[r] = rc[r]; rc[r] = rn[r]; }
    }
}

// ------------- MLP dwconv3x3 + skip + exact GELU; 2 ch/thread, 2 rows/block, ring -------------
// grid: dim3(4, 64, 2), 384 threads (ch pairs 0..383 -> channels 2t,2t+1).
__global__ __launch_bounds__(384) void dconv_gelu_row2(const ushort* __restrict__ hdn,
                                                       const float* __restrict__ w,
                                                       const float* __restrict__ bias,
                                                       ushort* __restrict__ out) {
    int xq = blockIdx.x, yq = blockIdx.y, bz = blockIdx.z;
    int c = threadIdx.x * 2;       // channels c, c+1
    int y0 = yq*2;

    float wA[9], wB[9];
    #pragma unroll
    for (int i = 0; i < 9; ++i) { wA[i] = w[c*9 + i]; wB[i] = w[(c+1)*9 + i]; }
    float bw0 = bias[c], bw1 = bias[c+1];

    const ushort* base = hdn + (size_t)bz*NN*HID + c;
    auto ld2 = [&](int yy, int xx) -> float2 {
        if ((unsigned)yy >= (unsigned)HH || (unsigned)xx >= (unsigned)WW2)
            return make_float2(0.f, 0.f);
        ushort2 u = *(const ushort2*)&base[((size_t)yy*WW2 + xx)*HID];
        return make_float2(bf2f(u.x), bf2f(u.y));
    };

    int x0 = xq*32;
    float2 rp[4], rc[4];
    #pragma unroll
    for (int r = 0; r < 4; ++r) {
        rp[r] = ld2(y0-1+r, x0-1);
        rc[r] = ld2(y0-1+r, x0);
    }

    #pragma unroll 4
    for (int i = 0; i < 32; ++i) {
        int x = x0 + i;
        float2 rn[4];
        #pragma unroll
        for (int r = 0; r < 4; ++r) rn[r] = ld2(y0-1+r, x+1);
        #pragma unroll
        for (int o = 0; o < 2; ++o) {
            float conv0 = bw0 + wA[0]*rp[o].x + wA[1]*rc[o].x + wA[2]*rn[o].x
                              + wA[3]*rp[o+1].x + wA[4]*rc[o+1].x + wA[5]*rn[o+1].x
                              + wA[6]*rp[o+2].x + wA[7]*rc[o+2].x + wA[8]*rn[o+2].x;
            float conv1 = bw1 + wB[0]*rp[o].y + wB[1]*rc[o].y + wB[2]*rn[o].y
                              + wB[3]*rp[o+1].y + wB[4]*rc[o+1].y + wB[5]*rn[o+1].y
                              + wB[6]*rp[o+2].y + wB[7]*rc[o+2].y + wB[8]*rn[o+2].y;
            float v0 = rc[o+1].x + conv0;   // center tap = skip
            float v1 = rc[o+1].y + conv1;
            ushort2 res;
            res.x = f2bf(0.5f*v0*(1.f + erff(v0*0.70710678118654752f)));
            res.y = f2bf(0.5f*v1*(1.f + erff(v1*0.70710678118654752f)));
            size_t n = (size_t)bz*NN + (size_t)(y0+o)*WW2 + x;
            *(ushort2*)&out[n*HID + c] = res;
        }
        #pragma unroll
        for (int r = 0; r < 4; ++r) { rp[r] = rc[r]; rc[r] = rn[r]; }
    }
}

extern "C" void kernel_launch(void* const* d_in, const int* in_sizes, int n_in,
                              void* d_out, int out_size, void* d_ws, size_t ws_size,
                              hipStream_t stream) {
    const float* x      = (const float*)d_in[0];
    const float* ln1_g  = (const float*)d_in[3];
    const float* ln1_b  = (const float*)d_in[4];
    const float* qkv_w  = (const float*)d_in[5];
    const float* qkv_b  = (const float*)d_in[6];
    const float* crpe_w = (const float*)d_in[7];
    const float* crpe_b = (const float*)d_in[8];
    const float* proj_w = (const float*)d_in[9];
    const float* proj_b = (const float*)d_in[10];
    const float* ln2_g  = (const float*)d_in[11];
    const float* ln2_b  = (const float*)d_in[12];
    const float* fc1_w  = (const float*)d_in[13];
    const float* fc1_b  = (const float*)d_in[14];
    const float* dconv_w= (const float*)d_in[15];
    const float* dconv_b= (const float*)d_in[16];
    const float* fc2_w  = (const float*)d_in[17];
    const float* fc2_b  = (const float*)d_in[18];
    float* outF = (float*)d_out;
    ushort* ws16 = (ushort*)d_ws;

    // Workspace arena (ushort units) — ~170 MB
    ushort* aq    = ws16;                    // 33,554,432  [B*N,512]: q | gate
    ushort* kbuf  = aq + 33554432;           // 16,777,216
    ushort* vbuf  = kbuf + 16777216;         // 16,777,216
    ushort* sbuf  = vbuf + 16777216;         // 16,777,216  (ln1 out / ln2 out)
    ushort* wqkvT = sbuf + 16777216;         // 196,608
    ushort* wfc1T = wqkvT + 196608;          // 196,608
    ushort* wfc2T = wfc1T + 196608;          // 196,608
    ushort* Bcat  = wfc2T + 196608;          // 524,288  [4][256][512] = WbT | projT
    float*  kvraw = (float*)(Bcat + 524288); // 32,768 f32
    float*  ksumB = kvraw + 32768;           // 1,024 f32
    ushort* hdn   = ws16;                    // alias aq+kbuf: 50,331,648 (after attn done)
    ushort* hdn2  = vbuf;                    // alias vbuf + dead sbuf head: 25,165,824

    const int ROWS = BB*NN;   // 65536

    // ---- weight prep ----
    wtrans<<<dim3(8,24), 256, 0, stream>>>(qkv_w,  wqkvT, CC,  3*CC);
    wtrans<<<dim3(8,24), 256, 0, stream>>>(fc1_w,  wfc1T, CC,  HID);
    wtrans<<<dim3(24,8), 256, 0, stream>>>(fc2_w,  wfc2T, HID, CC);
    wtrans_proj<<<dim3(8,8), 256, 0, stream>>>(proj_w, Bcat);

    // ---- attention branch ----
    ln_bf16v<<<ROWS/4, 256, 0, stream>>>(x, ln1_g, ln1_b, sbuf);
    mfma_gemm<256, 2><<<dim3(6, 512), 256, 0, stream>>>(
        sbuf, wqkvT, qkv_b, nullptr, aq, kbuf, vbuf, 0);
    zero_kernel<<<132, 256, 0, stream>>>(kvraw, 32768 + 1024);
    kv_accum<<<BB*NH*16, 256, 0, stream>>>(kbuf, vbuf, kvraw, ksumB);
    kv_fold<<<32, 256, 0, stream>>>(kvraw, ksumB, proj_w, Bcat);
    attn_gate<<<dim3(4, 64, 4), 256, 0, stream>>>(vbuf, crpe_w, crpe_b, aq);
    // x2 = x + q@Wb + g@proj_w + proj_b  -> d_out (fp32)
    mfma_gemm_attn<<<dim3(2, 128, 4), 256, 0, stream>>>(aq, Bcat, proj_b, x, outF);

    // ---- conv-MLP branch ----
    ln_bf16v<<<ROWS/4, 256, 0, stream>>>(outF, ln2_g, ln2_b, sbuf);
    mfma_gemm<256, 0><<<dim3(6, 512), 256, 0, stream>>>(
        sbuf, wfc1T, fc1_b, nullptr, hdn, nullptr, nullptr, 768);
    for (int p = 0; p < 2; ++p) {
        const ushort* hdn_p = hdn + (size_t)p*2*NN*HID;
        float* xo = outF + (size_t)p*2*NN*CC;
        dconv_gelu_row2<<<dim3(4, 64, 2), 384, 0, stream>>>(hdn_p, dconv_w, dconv_b, hdn2);
        // out = x2 + hdn2 @ fc2_w, in-place on d_out
        mfma_gemm<768, 1><<<dim3(2, 256), 256, 0, stream>>>(
            hdn2, wfc2T, fc2_b, xo, xo, nullptr, nullptr, 256);
    }
}

// Round 7
// 651.719 us; speedup vs baseline: 1.0160x; 1.0160x over previous
//
#include <hip/hip_runtime.h>
#include <math.h>

// Problem constants (setup_inputs is fixed)
#define BB   4
#define HH   128
#define WW2  128
#define NN   (HH*WW2)     // 16384
#define CC   256
#define NH   8
#define HID  768
#define EPSF 1e-6f
#define SCALE 0.17677669529663687f   // 32^-0.5

typedef __attribute__((ext_vector_type(8))) short s8v;   // 8 bf16 (4 VGPRs) MFMA A/B frag
typedef __attribute__((ext_vector_type(4))) float f4v;   // MFMA C/D frag

// ---- bf16 helpers (raw ushort storage) ----
__device__ __forceinline__ float bf2f(ushort h) {
    union { unsigned u; float f; } x; x.u = ((unsigned)h) << 16; return x.f;
}
__device__ __forceinline__ ushort f2bf(float f) {
    union { float f; unsigned u; } x; x.f = f;
    unsigned r = (x.u + 0x7FFFu + ((x.u >> 16) & 1u)) >> 16;
    return (ushort)r;
}

typedef __attribute__((address_space(1))) unsigned gu32;
typedef __attribute__((address_space(3))) unsigned lu32;
__device__ __forceinline__ void gl_lds16(const void* g, void* l) {
    __builtin_amdgcn_global_load_lds((gu32*)g, (lu32*)l, 16, 0, 0);
}

// ---------------- LayerNorm -> bf16, 4 rows per block, vectorized ----------------
__global__ __launch_bounds__(256) void ln_bf16v(const float* __restrict__ in,
                                                const float* __restrict__ g,
                                                const float* __restrict__ bta,
                                                ushort* __restrict__ out) {
    int row  = blockIdx.x*4 + (threadIdx.x >> 6);
    int lane = threadIdx.x & 63;
    const float* p = in + (size_t)row*CC + lane*4;
    float4 v = *(const float4*)p;
    float s  = v.x + v.y + v.z + v.w;
    float s2 = v.x*v.x + v.y*v.y + v.z*v.z + v.w*v.w;
    #pragma unroll
    for (int off = 32; off >= 1; off >>= 1) {
        s  += __shfl_xor(s, off);
        s2 += __shfl_xor(s2, off);
    }
    float mean = s * (1.0f/CC);
    float var  = s2 * (1.0f/CC) - mean*mean;
    float r    = rsqrtf(var + EPSF);
    float4 gv = *(const float4*)&g[lane*4];
    float4 bv = *(const float4*)&bta[lane*4];
    ushort4 o;
    o.x = f2bf((v.x-mean)*r*gv.x + bv.x);
    o.y = f2bf((v.y-mean)*r*gv.y + bv.y);
    o.z = f2bf((v.z-mean)*r*gv.z + bv.z);
    o.w = f2bf((v.w-mean)*r*gv.w + bv.w);
    *(ushort4*)&out[(size_t)row*CC + lane*4] = o;
}

// ---------------- LDS-tiled weight transpose + bf16 cast: w[K][N] -> wt[N][K] ----------------
__global__ __launch_bounds__(256) void wtrans(const float* __restrict__ w,
                                              ushort* __restrict__ wt, int K, int N) {
    __shared__ float tile[32][33];
    int k0 = blockIdx.x*32, n0 = blockIdx.y*32;
    int c = threadIdx.x & 31, r8 = threadIdx.x >> 5;
    #pragma unroll
    for (int r = 0; r < 4; ++r) {
        int kk = r8 + r*8;
        tile[kk][c] = w[(size_t)(k0+kk)*N + n0 + c];
    }
    __syncthreads();
    #pragma unroll
    for (int r = 0; r < 4; ++r) {
        int nn = r8 + r*8;
        wt[(size_t)(n0+nn)*K + k0 + c] = f2bf(tile[c][nn]);
    }
}

// ---- proj_w[K=256][N=256] -> Bcat[b][n][256+k] (projT half of concatenated B), 4 copies ----
__global__ __launch_bounds__(256) void wtrans_proj(const float* __restrict__ w,
                                                   ushort* __restrict__ Bcat) {
    __shared__ float tile[32][33];
    int k0 = blockIdx.x*32, n0 = blockIdx.y*32;
    int c = threadIdx.x & 31, r8 = threadIdx.x >> 5;
    #pragma unroll
    for (int r = 0; r < 4; ++r) {
        int kk = r8 + r*8;
        tile[kk][c] = w[(size_t)(k0+kk)*CC + n0 + c];
    }
    __syncthreads();
    #pragma unroll
    for (int r = 0; r < 4; ++r) {
        int nn = r8 + r*8;
        ushort val = f2bf(tile[c][nn]);
        #pragma unroll
        for (int b = 0; b < BB; ++b)
            Bcat[((size_t)(b*256 + n0+nn))*512 + 256 + k0 + c] = val;
    }
}

// ---------------- bf16 MFMA GEMM: C[M,N] = A[M,K] @ Bt[N,K]^T + bias (+resid) ----------------
// Counted-vmcnt pipeline (T3+T4): 3 LDS slots, prefetch distance 2, vmcnt(4) per step
// (never 0 in main loop); one s_barrier per K-step. XCD-aware block swizzle.
// MODE 0: bf16 out, stride NDIM.  MODE 1: f32 out = acc+bias+resid, stride NDIM.
// MODE 2: qkv split writer: col<256 -> aq (stride 512); col<512 -> kbuf; else vbuf (stride 256).
template<int KDIM, int MODE>
__global__ __launch_bounds__(256) void mfma_gemm(const ushort* __restrict__ A,
                                                 const ushort* __restrict__ Bt,
                                                 const float* __restrict__ bias,
                                                 const float* __restrict__ resid,
                                                 void* __restrict__ Cout,
                                                 ushort* __restrict__ kbuf,
                                                 ushort* __restrict__ vbuf,
                                                 int NDIM) {
    __shared__ ushort lsA[3][128*32];
    __shared__ ushort lsB[3][128*32];
    int tid  = threadIdx.x;
    int lane = tid & 63;
    int w    = tid >> 6;
    int wm   = w >> 1, wn = w & 1;

    // XCD swizzle: contiguous chunk of linear block ids per XCD (nwg % 8 == 0)
    int nwg = gridDim.x * gridDim.y;
    int lin = blockIdx.y * gridDim.x + blockIdx.x;
    int swz = (lin & 7) * (nwg >> 3) + (lin >> 3);
    int bx  = swz % gridDim.x;
    int by  = swz / gridDim.x;

    size_t mBase = (size_t)by * 128;
    int    nBase = bx * 128;
    int lrow = lane & 15, lq = lane >> 4;

    const ushort* gA = A  + (mBase + w*32 + (lane>>2))*(size_t)KDIM + (lane&3)*8;
    const ushort* gB = Bt + ((size_t)(nBase + w*32 + (lane>>2)))*(size_t)KDIM + (lane&3)*8;

    constexpr int NT = KDIM/32;

    // Each wave stages its own 1 KB quadrant of each slot (linear dest, gl_lds).
    auto STAGE = [&](int t) {
        const int k1 = t*32;
        ushort* dA = lsA[t%3] + w*1024;
        ushort* dB = lsB[t%3] + w*1024;
        gl_lds16(gA + k1,           dA);
        gl_lds16(gA + k1 + 16*KDIM, dA + 512);
        gl_lds16(gB + k1,           dB);
        gl_lds16(gB + k1 + 16*KDIM, dB + 512);
    };

    f4v acc[4][4] = {};

    // prologue: tiles 0 and 1 in flight (8 loads)
    STAGE(0);
    STAGE(1);

    #pragma unroll
    for (int kk = 0; kk < NT; ++kk) {
        // Wait for tile kk only (oldest 4 loads); tile kk+1's 4 stay in flight.
        if (kk < NT-1) asm volatile("s_waitcnt vmcnt(4)" ::: "memory");
        else           asm volatile("s_waitcnt vmcnt(0)" ::: "memory");
        __builtin_amdgcn_s_barrier();   // all waves' tile-kk quadrants visible;
                                        // all waves done reading slot (kk-1)%3
        if (kk+2 < NT) STAGE(kk+2);     // safe: writes slot (kk+2)%3 == (kk-1)%3

        const int cur = kk % 3;
        s8v af[4], bfr[4];
        #pragma unroll
        for (int i = 0; i < 4; ++i)
            af[i] = *(const s8v*)&lsA[cur][(wm*64 + i*16 + lrow)*32 + lq*8];
        #pragma unroll
        for (int j = 0; j < 4; ++j)
            bfr[j] = *(const s8v*)&lsB[cur][(wn*64 + j*16 + lrow)*32 + lq*8];
        #pragma unroll
        for (int i = 0; i < 4; ++i)
            #pragma unroll
            for (int j = 0; j < 4; ++j)
                acc[i][j] = __builtin_amdgcn_mfma_f32_16x16x32_bf16(af[i], bfr[j], acc[i][j], 0, 0, 0);
    }

    int colBase = nBase + wn*64;
    #pragma unroll
    for (int j = 0; j < 4; ++j) {
        int col = colBase + j*16 + lrow;
        float bs = bias[col];
        #pragma unroll
        for (int i = 0; i < 4; ++i) {
            #pragma unroll
            for (int r = 0; r < 4; ++r) {
                size_t row = mBase + wm*64 + i*16 + lq*4 + r;
                float v = acc[i][j][r] + bs;
                if constexpr (MODE == 0) {
                    ((ushort*)Cout)[row*(size_t)NDIM + col] = f2bf(v);
                } else if constexpr (MODE == 1) {
                    size_t idx = row*(size_t)NDIM + col;
                    ((float*)Cout)[idx] = v + resid[idx];
                } else {
                    if (col < 256)      ((ushort*)Cout)[row*512 + col] = f2bf(v);
                    else if (col < 512) kbuf[row*256 + col - 256] = f2bf(v);
                    else                vbuf[row*256 + col - 512] = f2bf(v);
                }
            }
        }
    }
}

// ---- attention proj GEMM: A=aq[B*N,512] contiguous, B=Bcat per batch, K=512 ----
__global__ __launch_bounds__(256) void mfma_gemm_attn(const ushort* __restrict__ aq,
                                                      const ushort* __restrict__ Bcat,
                                                      const float* __restrict__ bias,
                                                      const float* __restrict__ resid,
                                                      float* __restrict__ Cout) {
    __shared__ ushort lsA[3][128*32];
    __shared__ ushort lsB[3][128*32];
    int tid  = threadIdx.x;
    int lane = tid & 63;
    int w    = tid >> 6;
    int wm   = w >> 1, wn = w & 1;
    int b = blockIdx.z;

    // XCD swizzle within the per-batch 2D grid (2*128 = 256 blocks, %8==0)
    int nwg = gridDim.x * gridDim.y;
    int lin = blockIdx.y * gridDim.x + blockIdx.x;
    int swz = (lin & 7) * (nwg >> 3) + (lin >> 3);
    int bx  = swz % gridDim.x;
    int by  = swz / gridDim.x;

    size_t mBase = (size_t)b*NN + (size_t)by * 128;
    int    nBase = bx * 128;
    int lrow = lane & 15, lq = lane >> 4;

    const ushort* gA = aq + (mBase + w*32 + (lane>>2))*512 + (lane&3)*8;
    const ushort* gB = Bcat + ((size_t)(b*256 + nBase + w*32 + (lane>>2)))*512 + (lane&3)*8;

    constexpr int NT = 512/32;

    auto STAGE = [&](int t) {
        const int k1 = t*32;
        ushort* dA = lsA[t%3] + w*1024;
        ushort* dB = lsB[t%3] + w*1024;
        gl_lds16(gA + k1,          dA);
        gl_lds16(gA + k1 + 16*512, dA + 512);
        gl_lds16(gB + k1,          dB);
        gl_lds16(gB + k1 + 16*512, dB + 512);
    };

    f4v acc[4][4] = {};

    STAGE(0);
    STAGE(1);

    #pragma unroll
    for (int kk = 0; kk < NT; ++kk) {
        if (kk < NT-1) asm volatile("s_waitcnt vmcnt(4)" ::: "memory");
        else           asm volatile("s_waitcnt vmcnt(0)" ::: "memory");
        __builtin_amdgcn_s_barrier();
        if (kk+2 < NT) STAGE(kk+2);

        const int cur = kk % 3;
        s8v af[4], bfr[4];
        #pragma unroll
        for (int i = 0; i < 4; ++i)
            af[i] = *(const s8v*)&lsA[cur][(wm*64 + i*16 + lrow)*32 + lq*8];
        #pragma unroll
        for (int j = 0; j < 4; ++j)
            bfr[j] = *(const s8v*)&lsB[cur][(wn*64 + j*16 + lrow)*32 + lq*8];
        #pragma unroll
        for (int i = 0; i < 4; ++i)
            #pragma unroll
            for (int j = 0; j < 4; ++j)
                acc[i][j] = __builtin_amdgcn_mfma_f32_16x16x32_bf16(af[i], bfr[j], acc[i][j], 0, 0, 0);
    }

    int colBase = nBase + wn*64;
    #pragma unroll
    for (int j = 0; j < 4; ++j) {
        int col = colBase + j*16 + lrow;
        float bs = bias[col];
        #pragma unroll
        for (int i = 0; i < 4; ++i) {
            #pragma unroll
            for (int r = 0; r < 4; ++r) {
                size_t row = mBase + wm*64 + i*16 + lq*4 + r;
                size_t idx = row*(size_t)CC + col;
                Cout[idx] = acc[i][j][r] + bs + resid[idx];
            }
        }
    }
}

__global__ void zero_kernel(float* __restrict__ p, int nElems) {
    int i = blockIdx.x*256 + threadIdx.x;
    if (i < nElems) p[i] = 0.f;
}

// ------------- kv_raw[bh,kd,vd] += sum_n exp(k)*v ; ksum[bh,kd] += sum_n exp(k) -------------
// (no max-shift: |k| <~ 3 so exp() is safe in fp32; softmax is shift-invariant)
__global__ __launch_bounds__(256) void kv_accum(const ushort* __restrict__ kbuf,
                                                const ushort* __restrict__ vbuf,
                                                float* __restrict__ kv_raw,
                                                float* __restrict__ ksum) {
    int blk = blockIdx.x;
    int chunk = blk & 15;
    int bh = blk >> 4;
    int b = bh >> 3, hh = bh & 7;
    int tid = threadIdx.x;
    __shared__ float ke[32][36];
    __shared__ float vv[32][36];
    int tok = tid >> 3;           // 0..31 staging token
    int c4  = (tid & 7) * 4;      // staging channels
    int kd  = tid >> 3;           // compute: fixed k-channel
    int v0  = (tid & 7) * 4;      // compute: 4 v-channels
    float acc0=0.f, acc1=0.f, acc2=0.f, acc3=0.f, ks=0.f;
    for (int it = 0; it < 32; ++it) {
        int nb = chunk*1024 + it*32;
        size_t rowoff = ((size_t)b*NN + nb + tok)*256 + hh*32 + c4;
        ushort4 k4 = *(const ushort4*)&kbuf[rowoff];
        ushort4 v4 = *(const ushort4*)&vbuf[rowoff];
        float4 kf, vf;
        kf.x = expf(bf2f(k4.x)); kf.y = expf(bf2f(k4.y));
        kf.z = expf(bf2f(k4.z)); kf.w = expf(bf2f(k4.w));
        vf.x = bf2f(v4.x); vf.y = bf2f(v4.y); vf.z = bf2f(v4.z); vf.w = bf2f(v4.w);
        *(float4*)&ke[tok][c4] = kf;
        *(float4*)&vv[tok][c4] = vf;
        __syncthreads();
        #pragma unroll
        for (int tt = 0; tt < 32; ++tt) {
            float kval = ke[tt][kd];
            float4 vr = *(const float4*)&vv[tt][v0];
            ks   += kval;
            acc0 += kval*vr.x;
            acc1 += kval*vr.y;
            acc2 += kval*vr.z;
            acc3 += kval*vr.w;
        }
        __syncthreads();
    }
    float* dst = kv_raw + ((size_t)bh*32 + kd)*32 + v0;
    atomicAdd(dst+0, acc0); atomicAdd(dst+1, acc1);
    atomicAdd(dst+2, acc2); atomicAdd(dst+3, acc3);
    if (v0 == 0) atomicAdd(&ksum[bh*32 + kd], ks);
}

// ------------- fold: Bcat[b][j][h*32+kd] = SCALE * sum_vd (kv/ksum)[b,h,kd,vd] * proj_w[h*32+vd][j] -------------
__global__ __launch_bounds__(256) void kv_fold(const float* __restrict__ kv_raw,
                                               const float* __restrict__ ksum,
                                               const float* __restrict__ proj_w,
                                               ushort* __restrict__ Bcat) {
    int bh = blockIdx.x;           // 0..31
    int b = bh >> 3, hh = bh & 7;
    int tid = threadIdx.x;         // j = tid
    __shared__ float kvn[32][33];
    __shared__ float pw[32][256];
    {
        int kd = tid >> 3, v4 = (tid & 7) * 4;
        float inv = 1.0f / ksum[bh*32 + kd];
        const float* src = kv_raw + ((size_t)bh*32 + kd)*32 + v4;
        kvn[kd][v4+0] = src[0]*inv; kvn[kd][v4+1] = src[1]*inv;
        kvn[kd][v4+2] = src[2]*inv; kvn[kd][v4+3] = src[3]*inv;
    }
    for (int vd = 0; vd < 32; ++vd)
        pw[vd][tid] = proj_w[(size_t)(hh*32 + vd)*CC + tid];
    __syncthreads();
    ushort* dst = Bcat + ((size_t)(b*256 + tid))*512 + hh*32;
    for (int kd = 0; kd < 32; ++kd) {
        float acc = 0.f;
        #pragma unroll
        for (int vd = 0; vd < 32; ++vd) acc += kvn[kd][vd] * pw[vd][tid];
        dst[kd] = f2bf(SCALE * acc);
    }
}

// ------------- g = q * (dwconv3x3(v)+bias) -> aq[:,256:512]; 2 rows/block, ring -------------
// grid: (xq=4, yq=64, b=4), 256 threads = channels.
__global__ __launch_bounds__(256) void attn_gate(const ushort* __restrict__ vbuf,
                                                 const float* __restrict__ w,
                                                 const float* __restrict__ wb,
                                                 ushort* __restrict__ aq) {
    int xq = blockIdx.x, yq = blockIdx.y, b = blockIdx.z;
    int c = threadIdx.x;
    int y0 = yq*2;

    const float* wc = w + c*9;
    float w00=wc[0], w01=wc[1], w02=wc[2],
          w10=wc[3], w11=wc[4], w12=wc[5],
          w20=wc[6], w21=wc[7], w22=wc[8];
    float bw = wb[c];

    const ushort* vbase = vbuf + (size_t)b*NN*256 + c;
    auto ldv = [&](int yy, int xx) -> float {
        if ((unsigned)yy >= (unsigned)HH || (unsigned)xx >= (unsigned)WW2) return 0.f;
        return bf2f(vbase[((size_t)yy*WW2 + xx)*256]);
    };

    int x0 = xq*32;
    float rp[4], rc[4];
    #pragma unroll
    for (int r = 0; r < 4; ++r) {
        rp[r] = ldv(y0-1+r, x0-1);
        rc[r] = ldv(y0-1+r, x0);
    }

    #pragma unroll 4
    for (int i = 0; i < 32; ++i) {
        int x = x0 + i;
        float rn[4];
        #pragma unroll
        for (int r = 0; r < 4; ++r) rn[r] = ldv(y0-1+r, x+1);
        #pragma unroll
        for (int o = 0; o < 2; ++o) {
            float conv = bw + w00*rp[o] + w01*rc[o] + w02*rn[o]
                            + w10*rp[o+1] + w11*rc[o+1] + w12*rn[o+1]
                            + w20*rp[o+2] + w21*rc[o+2] + w22*rn[o+2];
            size_t bn = (size_t)b*NN + (size_t)(y0+o)*WW2 + x;
            float qc = bf2f(aq[bn*512 + c]);
            aq[bn*512 + 256 + c] = f2bf(qc*conv);
        }
        #pragma unroll
        for (int r = 0; r < 4; ++r) { rp[r] = rc[r]; rc[r] = rn[r]; }
    }
}

// ------------- MLP dwconv3x3 + skip + exact GELU; 2 ch/thread, 2 rows/block, ring -------------
// grid: dim3(4, 64, 2), 384 threads (ch pairs 0..383 -> channels 2t,2t+1).
__global__ __launch_bounds__(384) void dconv_gelu_row2(const ushort* __restrict__ hdn,
                                                       const float* __restrict__ w,
                                                       const float* __restrict__ bias,
                                                       ushort* __restrict__ out) {
    int xq = blockIdx.x, yq = blockIdx.y, bz = blockIdx.z;
    int c = threadIdx.x * 2;       // channels c, c+1
    int y0 = yq*2;

    float wA[9], wB[9];
    #pragma unroll
    for (int i = 0; i < 9; ++i) { wA[i] = w[c*9 + i]; wB[i] = w[(c+1)*9 + i]; }
    float bw0 = bias[c], bw1 = bias[c+1];

    const ushort* base = hdn + (size_t)bz*NN*HID + c;
    auto ld2 = [&](int yy, int xx) -> float2 {
        if ((unsigned)yy >= (unsigned)HH || (unsigned)xx >= (unsigned)WW2)
            return make_float2(0.f, 0.f);
        ushort2 u = *(const ushort2*)&base[((size_t)yy*WW2 + xx)*HID];
        return make_float2(bf2f(u.x), bf2f(u.y));
    };

    int x0 = xq*32;
    float2 rp[4], rc[4];
    #pragma unroll
    for (int r = 0; r < 4; ++r) {
        rp[r] = ld2(y0-1+r, x0-1);
        rc[r] = ld2(y0-1+r, x0);
    }

    #pragma unroll 4
    for (int i = 0; i < 32; ++i) {
        int x = x0 + i;
        float2 rn[4];
        #pragma unroll
        for (int r = 0; r < 4; ++r) rn[r] = ld2(y0-1+r, x+1);
        #pragma unroll
        for (int o = 0; o < 2; ++o) {
            float conv0 = bw0 + wA[0]*rp[o].x + wA[1]*rc[o].x + wA[2]*rn[o].x
                              + wA[3]*rp[o+1].x + wA[4]*rc[o+1].x + wA[5]*rn[o+1].x
                              + wA[6]*rp[o+2].x + wA[7]*rc[o+2].x + wA[8]*rn[o+2].x;
            float conv1 = bw1 + wB[0]*rp[o].y + wB[1]*rc[o].y + wB[2]*rn[o].y
                              + wB[3]*rp[o+1].y + wB[4]*rc[o+1].y + wB[5]*rn[o+1].y
                              + wB[6]*rp[o+2].y + wB[7]*rc[o+2].y + wB[8]*rn[o+2].y;
            float v0 = rc[o+1].x + conv0;   // center tap = skip
            float v1 = rc[o+1].y + conv1;
            ushort2 res;
            res.x = f2bf(0.5f*v0*(1.f + erff(v0*0.70710678118654752f)));
            res.y = f2bf(0.5f*v1*(1.f + erff(v1*0.70710678118654752f)));
            size_t n = (size_t)bz*NN + (size_t)(y0+o)*WW2 + x;
            *(ushort2*)&out[n*HID + c] = res;
        }
        #pragma unroll
        for (int r = 0; r < 4; ++r) { rp[r] = rc[r]; rc[r] = rn[r]; }
    }
}

extern "C" void kernel_launch(void* const* d_in, const int* in_sizes, int n_in,
                              void* d_out, int out_size, void* d_ws, size_t ws_size,
                              hipStream_t stream) {
    const float* x      = (const float*)d_in[0];
    const float* ln1_g  = (const float*)d_in[3];
    const float* ln1_b  = (const float*)d_in[4];
    const float* qkv_w  = (const float*)d_in[5];
    const float* qkv_b  = (const float*)d_in[6];
    const float* crpe_w = (const float*)d_in[7];
    const float* crpe_b = (const float*)d_in[8];
    const float* proj_w = (const float*)d_in[9];
    const float* proj_b = (const float*)d_in[10];
    const float* ln2_g  = (const float*)d_in[11];
    const float* ln2_b  = (const float*)d_in[12];
    const float* fc1_w  = (const float*)d_in[13];
    const float* fc1_b  = (const float*)d_in[14];
    const float* dconv_w= (const float*)d_in[15];
    const float* dconv_b= (const float*)d_in[16];
    const float* fc2_w  = (const float*)d_in[17];
    const float* fc2_b  = (const float*)d_in[18];
    float* outF = (float*)d_out;
    ushort* ws16 = (ushort*)d_ws;

    // Workspace arena (ushort units) — ~170 MB
    ushort* aq    = ws16;                    // 33,554,432  [B*N,512]: q | gate
    ushort* kbuf  = aq + 33554432;           // 16,777,216
    ushort* vbuf  = kbuf + 16777216;         // 16,777,216
    ushort* sbuf  = vbuf + 16777216;         // 16,777,216  (ln1 out / ln2 out)
    ushort* wqkvT = sbuf + 16777216;         // 196,608
    ushort* wfc1T = wqkvT + 196608;          // 196,608
    ushort* wfc2T = wfc1T + 196608;          // 196,608
    ushort* Bcat  = wfc2T + 196608;          // 524,288  [4][256][512] = WbT | projT
    float*  kvraw = (float*)(Bcat + 524288); // 32,768 f32
    float*  ksumB = kvraw + 32768;           // 1,024 f32
    ushort* hdn   = ws16;                    // alias aq+kbuf: 50,331,648 (after attn done)
    ushort* hdn2  = vbuf;                    // alias vbuf + dead sbuf head: 25,165,824

    const int ROWS = BB*NN;   // 65536

    // ---- weight prep ----
    wtrans<<<dim3(8,24), 256, 0, stream>>>(qkv_w,  wqkvT, CC,  3*CC);
    wtrans<<<dim3(8,24), 256, 0, stream>>>(fc1_w,  wfc1T, CC,  HID);
    wtrans<<<dim3(24,8), 256, 0, stream>>>(fc2_w,  wfc2T, HID, CC);
    wtrans_proj<<<dim3(8,8), 256, 0, stream>>>(proj_w, Bcat);

    // ---- attention branch ----
    ln_bf16v<<<ROWS/4, 256, 0, stream>>>(x, ln1_g, ln1_b, sbuf);
    mfma_gemm<256, 2><<<dim3(6, 512), 256, 0, stream>>>(
        sbuf, wqkvT, qkv_b, nullptr, aq, kbuf, vbuf, 0);
    zero_kernel<<<132, 256, 0, stream>>>(kvraw, 32768 + 1024);
    kv_accum<<<BB*NH*16, 256, 0, stream>>>(kbuf, vbuf, kvraw, ksumB);
    kv_fold<<<32, 256, 0, stream>>>(kvraw, ksumB, proj_w, Bcat);
    attn_gate<<<dim3(4, 64, 4), 256, 0, stream>>>(vbuf, crpe_w, crpe_b, aq);
    // x2 = x + q@Wb + g@proj_w + proj_b  -> d_out (fp32)
    mfma_gemm_attn<<<dim3(2, 128, 4), 256, 0, stream>>>(aq, Bcat, proj_b, x, outF);

    // ---- conv-MLP branch ----
    ln_bf16v<<<ROWS/4, 256, 0, stream>>>(outF, ln2_g, ln2_b, sbuf);
    mfma_gemm<256, 0><<<dim3(6, 512), 256, 0, stream>>>(
        sbuf, wfc1T, fc1_b, nullptr, hdn, nullptr, nullptr, 768);
    for (int p = 0; p < 2; ++p) {
        const ushort* hdn_p = hdn + (size_t)p*2*NN*HID;
        float* xo = outF + (size_t)p*2*NN*CC;
        dconv_gelu_row2<<<dim3(4, 64, 2), 384, 0, stream>>>(hdn_p, dconv_w, dconv_b, hdn2);
        // out = x2 + hdn2 @ fc2_w, in-place on d_out
        mfma_gemm<768, 1><<<dim3(2, 256), 256, 0, stream>>>(
            hdn2, wfc2T, fc2_b, xo, xo, nullptr, nullptr, 256);
    }
}

// Round 8
// 581.845 us; speedup vs baseline: 1.1380x; 1.1201x over previous
//
#include <hip/hip_runtime.h>
#include <math.h>

// Problem constants (setup_inputs is fixed)
#define BB   4
#define HH   128
#define WW2  128
#define NN   (HH*WW2)     // 16384
#define CC   256
#define NH   8
#define HID  768
#define EPSF 1e-6f
#define SCALE 0.17677669529663687f   // 32^-0.5

typedef __attribute__((ext_vector_type(8))) short s8v;   // 8 bf16 (4 VGPRs) MFMA A/B frag
typedef __attribute__((ext_vector_type(4))) float f4v;   // MFMA C/D frag

// ---- bf16 helpers (raw ushort storage) ----
__device__ __forceinline__ float bf2f(ushort h) {
    union { unsigned u; float f; } x; x.u = ((unsigned)h) << 16; return x.f;
}
__device__ __forceinline__ ushort f2bf(float f) {
    union { float f; unsigned u; } x; x.f = f;
    unsigned r = (x.u + 0x7FFFu + ((x.u >> 16) & 1u)) >> 16;
    return (ushort)r;
}

typedef __attribute__((address_space(1))) unsigned gu32;
typedef __attribute__((address_space(3))) unsigned lu32;
__device__ __forceinline__ void gl_lds16(const void* g, void* l) {
    __builtin_amdgcn_global_load_lds((gu32*)g, (lu32*)l, 16, 0, 0);
}

// ---------------- LayerNorm -> bf16, 4 rows per block, vectorized ----------------
__global__ __launch_bounds__(256) void ln_bf16v(const float* __restrict__ in,
                                                const float* __restrict__ g,
                                                const float* __restrict__ bta,
                                                ushort* __restrict__ out) {
    int row  = blockIdx.x*4 + (threadIdx.x >> 6);
    int lane = threadIdx.x & 63;
    const float* p = in + (size_t)row*CC + lane*4;
    float4 v = *(const float4*)p;
    float s  = v.x + v.y + v.z + v.w;
    float s2 = v.x*v.x + v.y*v.y + v.z*v.z + v.w*v.w;
    #pragma unroll
    for (int off = 32; off >= 1; off >>= 1) {
        s  += __shfl_xor(s, off);
        s2 += __shfl_xor(s2, off);
    }
    float mean = s * (1.0f/CC);
    float var  = s2 * (1.0f/CC) - mean*mean;
    float r    = rsqrtf(var + EPSF);
    float4 gv = *(const float4*)&g[lane*4];
    float4 bv = *(const float4*)&bta[lane*4];
    ushort4 o;
    o.x = f2bf((v.x-mean)*r*gv.x + bv.x);
    o.y = f2bf((v.y-mean)*r*gv.y + bv.y);
    o.z = f2bf((v.z-mean)*r*gv.z + bv.z);
    o.w = f2bf((v.w-mean)*r*gv.w + bv.w);
    *(ushort4*)&out[(size_t)row*CC + lane*4] = o;
}

// ---------------- LDS-tiled weight transpose + bf16 cast: w[K][N] -> wt[N][K] ----------------
__global__ __launch_bounds__(256) void wtrans(const float* __restrict__ w,
                                              ushort* __restrict__ wt, int K, int N) {
    __shared__ float tile[32][33];
    int k0 = blockIdx.x*32, n0 = blockIdx.y*32;
    int c = threadIdx.x & 31, r8 = threadIdx.x >> 5;
    #pragma unroll
    for (int r = 0; r < 4; ++r) {
        int kk = r8 + r*8;
        tile[kk][c] = w[(size_t)(k0+kk)*N + n0 + c];
    }
    __syncthreads();
    #pragma unroll
    for (int r = 0; r < 4; ++r) {
        int nn = r8 + r*8;
        wt[(size_t)(n0+nn)*K + k0 + c] = f2bf(tile[c][nn]);
    }
}

// ---- proj_w[K=256][N=256] -> Bcat[b][n][256+k] (projT half of concatenated B), 4 copies ----
__global__ __launch_bounds__(256) void wtrans_proj(const float* __restrict__ w,
                                                   ushort* __restrict__ Bcat) {
    __shared__ float tile[32][33];
    int k0 = blockIdx.x*32, n0 = blockIdx.y*32;
    int c = threadIdx.x & 31, r8 = threadIdx.x >> 5;
    #pragma unroll
    for (int r = 0; r < 4; ++r) {
        int kk = r8 + r*8;
        tile[kk][c] = w[(size_t)(k0+kk)*CC + n0 + c];
    }
    __syncthreads();
    #pragma unroll
    for (int r = 0; r < 4; ++r) {
        int nn = r8 + r*8;
        ushort val = f2bf(tile[c][nn]);
        #pragma unroll
        for (int b = 0; b < BB; ++b)
            Bcat[((size_t)(b*256 + n0+nn))*512 + 256 + k0 + c] = val;
    }
}

// ---------------- bf16 MFMA GEMM: C[M,N] = A[M,K] @ Bt[N,K]^T + bias (+resid) ----------------
// Round-0 single-buffer K-loop (16 KB LDS -> max blocks/CU; cross-block overlap hides
// staging latency, m114/m102) + XCD-aware block swizzle + j-inner epilogue (write combine).
// MODE 0: bf16 out, stride NDIM.  MODE 1: f32 out = acc+bias+resid, stride NDIM.
// MODE 2: qkv split writer: col<256 -> aq (stride 512); col<512 -> kbuf; else vbuf (stride 256).
template<int KDIM, int MODE>
__global__ __launch_bounds__(256) void mfma_gemm(const ushort* __restrict__ A,
                                                 const ushort* __restrict__ Bt,
                                                 const float* __restrict__ bias,
                                                 const float* __restrict__ resid,
                                                 void* __restrict__ Cout,
                                                 ushort* __restrict__ kbuf,
                                                 ushort* __restrict__ vbuf,
                                                 int NDIM) {
    __shared__ ushort lsA[128*32];
    __shared__ ushort lsB[128*32];
    int tid  = threadIdx.x;
    int lane = tid & 63;
    int w    = tid >> 6;
    int wm   = w >> 1, wn = w & 1;

    // XCD swizzle: HW block lin -> work swz s.t. work-consecutive blocks (sharing an
    // A-panel) land on the same XCD's contiguous chunk (nwg % 8 == 0).
    int nwg = gridDim.x * gridDim.y;
    int lin = blockIdx.y * gridDim.x + blockIdx.x;
    int swz = (lin & 7) * (nwg >> 3) + (lin >> 3);
    int bx  = swz % gridDim.x;
    int by  = swz / gridDim.x;

    size_t mBase = (size_t)by * 128;
    int    nBase = bx * 128;
    int lrow = lane & 15, lq = lane >> 4;

    const ushort* gA = A  + (mBase + w*32 + (lane>>2))*(size_t)KDIM + (lane&3)*8;
    const ushort* gB = Bt + ((size_t)(nBase + w*32 + (lane>>2)))*(size_t)KDIM + (lane&3)*8;
    ushort* lA = lsA + w*1024;
    ushort* lB = lsB + w*1024;

    f4v acc[4][4] = {};

    for (int k0 = 0; k0 < KDIM; k0 += 32) {
        gl_lds16(gA + k0,           lA);
        gl_lds16(gA + k0 + 16*KDIM, lA + 512);
        gl_lds16(gB + k0,           lB);
        gl_lds16(gB + k0 + 16*KDIM, lB + 512);
        __syncthreads();
        s8v af[4], bfr[4];
        #pragma unroll
        for (int i = 0; i < 4; ++i)
            af[i] = *(const s8v*)&lsA[(wm*64 + i*16 + lrow)*32 + lq*8];
        #pragma unroll
        for (int j = 0; j < 4; ++j)
            bfr[j] = *(const s8v*)&lsB[(wn*64 + j*16 + lrow)*32 + lq*8];
        #pragma unroll
        for (int i = 0; i < 4; ++i)
            #pragma unroll
            for (int j = 0; j < 4; ++j)
                acc[i][j] = __builtin_amdgcn_mfma_f32_16x16x32_bf16(af[i], bfr[j], acc[i][j], 0, 0, 0);
        __syncthreads();
    }

    // Epilogue: j innermost so the 4 column-chunks of each output row issue
    // back-to-back (complete cache lines -> less write amplification).
    int colBase = nBase + wn*64;
    float bs[4];
    #pragma unroll
    for (int j = 0; j < 4; ++j) bs[j] = bias[colBase + j*16 + lrow];
    #pragma unroll
    for (int i = 0; i < 4; ++i) {
        #pragma unroll
        for (int r = 0; r < 4; ++r) {
            size_t row = mBase + wm*64 + i*16 + lq*4 + r;
            #pragma unroll
            for (int j = 0; j < 4; ++j) {
                int col = colBase + j*16 + lrow;
                float v = acc[i][j][r] + bs[j];
                if constexpr (MODE == 0) {
                    ((ushort*)Cout)[row*(size_t)NDIM + col] = f2bf(v);
                } else if constexpr (MODE == 1) {
                    size_t idx = row*(size_t)NDIM + col;
                    ((float*)Cout)[idx] = v + resid[idx];
                } else {
                    if (col < 256)      ((ushort*)Cout)[row*512 + col] = f2bf(v);
                    else if (col < 512) kbuf[row*256 + col - 256] = f2bf(v);
                    else                vbuf[row*256 + col - 512] = f2bf(v);
                }
            }
        }
    }
}

// ---- attention proj GEMM: A=aq[B*N,512] contiguous, B=Bcat per batch, K=512 ----
__global__ __launch_bounds__(256) void mfma_gemm_attn(const ushort* __restrict__ aq,
                                                      const ushort* __restrict__ Bcat,
                                                      const float* __restrict__ bias,
                                                      const float* __restrict__ resid,
                                                      float* __restrict__ Cout) {
    __shared__ ushort lsA[128*32];
    __shared__ ushort lsB[128*32];
    int tid  = threadIdx.x;
    int lane = tid & 63;
    int w    = tid >> 6;
    int wm   = w >> 1, wn = w & 1;
    int b = blockIdx.z;

    // XCD swizzle within the per-batch 2D grid (2*128 = 256 blocks, %8==0; z*256%8==0
    // so HW XCD phase is preserved across z-slices).
    int nwg = gridDim.x * gridDim.y;
    int lin = blockIdx.y * gridDim.x + blockIdx.x;
    int swz = (lin & 7) * (nwg >> 3) + (lin >> 3);
    int bx  = swz % gridDim.x;
    int by  = swz / gridDim.x;

    size_t mBase = (size_t)b*NN + (size_t)by * 128;
    int    nBase = bx * 128;
    int lrow = lane & 15, lq = lane >> 4;

    const ushort* gA = aq + (mBase + w*32 + (lane>>2))*512 + (lane&3)*8;
    const ushort* gB = Bcat + ((size_t)(b*256 + nBase + w*32 + (lane>>2)))*512 + (lane&3)*8;
    ushort* lA = lsA + w*1024;
    ushort* lB = lsB + w*1024;

    f4v acc[4][4] = {};

    for (int k0 = 0; k0 < 512; k0 += 32) {
        gl_lds16(gA + k0,          lA);
        gl_lds16(gA + k0 + 16*512, lA + 512);
        gl_lds16(gB + k0,          lB);
        gl_lds16(gB + k0 + 16*512, lB + 512);
        __syncthreads();
        s8v af[4], bfr[4];
        #pragma unroll
        for (int i = 0; i < 4; ++i)
            af[i] = *(const s8v*)&lsA[(wm*64 + i*16 + lrow)*32 + lq*8];
        #pragma unroll
        for (int j = 0; j < 4; ++j)
            bfr[j] = *(const s8v*)&lsB[(wn*64 + j*16 + lrow)*32 + lq*8];
        #pragma unroll
        for (int i = 0; i < 4; ++i)
            #pragma unroll
            for (int j = 0; j < 4; ++j)
                acc[i][j] = __builtin_amdgcn_mfma_f32_16x16x32_bf16(af[i], bfr[j], acc[i][j], 0, 0, 0);
        __syncthreads();
    }

    int colBase = nBase + wn*64;
    float bs[4];
    #pragma unroll
    for (int j = 0; j < 4; ++j) bs[j] = bias[colBase + j*16 + lrow];
    #pragma unroll
    for (int i = 0; i < 4; ++i) {
        #pragma unroll
        for (int r = 0; r < 4; ++r) {
            size_t row = mBase + wm*64 + i*16 + lq*4 + r;
            #pragma unroll
            for (int j = 0; j < 4; ++j) {
                int col = colBase + j*16 + lrow;
                size_t idx = row*(size_t)CC + col;
                Cout[idx] = acc[i][j][r] + bs[j] + resid[idx];
            }
        }
    }
}

__global__ void zero_kernel(float* __restrict__ p, int nElems) {
    int i = blockIdx.x*256 + threadIdx.x;
    if (i < nElems) p[i] = 0.f;
}

// ------------- kv_raw[bh,kd,vd] += sum_n exp(k)*v ; ksum[bh,kd] += sum_n exp(k) -------------
// (no max-shift: |k| <~ 3 so exp() is safe in fp32; softmax is shift-invariant)
__global__ __launch_bounds__(256) void kv_accum(const ushort* __restrict__ kbuf,
                                                const ushort* __restrict__ vbuf,
                                                float* __restrict__ kv_raw,
                                                float* __restrict__ ksum) {
    int blk = blockIdx.x;
    int chunk = blk & 15;
    int bh = blk >> 4;
    int b = bh >> 3, hh = bh & 7;
    int tid = threadIdx.x;
    __shared__ float ke[32][36];
    __shared__ float vv[32][36];
    int tok = tid >> 3;           // 0..31 staging token
    int c4  = (tid & 7) * 4;      // staging channels
    int kd  = tid >> 3;           // compute: fixed k-channel
    int v0  = (tid & 7) * 4;      // compute: 4 v-channels
    float acc0=0.f, acc1=0.f, acc2=0.f, acc3=0.f, ks=0.f;
    for (int it = 0; it < 32; ++it) {
        int nb = chunk*1024 + it*32;
        size_t rowoff = ((size_t)b*NN + nb + tok)*256 + hh*32 + c4;
        ushort4 k4 = *(const ushort4*)&kbuf[rowoff];
        ushort4 v4 = *(const ushort4*)&vbuf[rowoff];
        float4 kf, vf;
        kf.x = expf(bf2f(k4.x)); kf.y = expf(bf2f(k4.y));
        kf.z = expf(bf2f(k4.z)); kf.w = expf(bf2f(k4.w));
        vf.x = bf2f(v4.x); vf.y = bf2f(v4.y); vf.z = bf2f(v4.z); vf.w = bf2f(v4.w);
        *(float4*)&ke[tok][c4] = kf;
        *(float4*)&vv[tok][c4] = vf;
        __syncthreads();
        #pragma unroll
        for (int tt = 0; tt < 32; ++tt) {
            float kval = ke[tt][kd];
            float4 vr = *(const float4*)&vv[tt][v0];
            ks   += kval;
            acc0 += kval*vr.x;
            acc1 += kval*vr.y;
            acc2 += kval*vr.z;
            acc3 += kval*vr.w;
        }
        __syncthreads();
    }
    float* dst = kv_raw + ((size_t)bh*32 + kd)*32 + v0;
    atomicAdd(dst+0, acc0); atomicAdd(dst+1, acc1);
    atomicAdd(dst+2, acc2); atomicAdd(dst+3, acc3);
    if (v0 == 0) atomicAdd(&ksum[bh*32 + kd], ks);
}

// ------------- fold: Bcat[b][j][h*32+kd] = SCALE * sum_vd (kv/ksum)[b,h,kd,vd] * proj_w[h*32+vd][j] -------------
__global__ __launch_bounds__(256) void kv_fold(const float* __restrict__ kv_raw,
                                               const float* __restrict__ ksum,
                                               const float* __restrict__ proj_w,
                                               ushort* __restrict__ Bcat) {
    int bh = blockIdx.x;           // 0..31
    int b = bh >> 3, hh = bh & 7;
    int tid = threadIdx.x;         // j = tid
    __shared__ float kvn[32][33];
    __shared__ float pw[32][256];
    {
        int kd = tid >> 3, v4 = (tid & 7) * 4;
        float inv = 1.0f / ksum[bh*32 + kd];
        const float* src = kv_raw + ((size_t)bh*32 + kd)*32 + v4;
        kvn[kd][v4+0] = src[0]*inv; kvn[kd][v4+1] = src[1]*inv;
        kvn[kd][v4+2] = src[2]*inv; kvn[kd][v4+3] = src[3]*inv;
    }
    for (int vd = 0; vd < 32; ++vd)
        pw[vd][tid] = proj_w[(size_t)(hh*32 + vd)*CC + tid];
    __syncthreads();
    ushort* dst = Bcat + ((size_t)(b*256 + tid))*512 + hh*32;
    for (int kd = 0; kd < 32; ++kd) {
        float acc = 0.f;
        #pragma unroll
        for (int vd = 0; vd < 32; ++vd) acc += kvn[kd][vd] * pw[vd][tid];
        dst[kd] = f2bf(SCALE * acc);
    }
}

// ------------- g = q * (dwconv3x3(v)+bias) -> aq[:,256:512]; 2 rows/block, ring -------------
// grid: (xq=4, yq=64, b=4), 256 threads = channels.
__global__ __launch_bounds__(256) void attn_gate(const ushort* __restrict__ vbuf,
                                                 const float* __restrict__ w,
                                                 const float* __restrict__ wb,
                                                 ushort* __restrict__ aq) {
    int xq = blockIdx.x, yq = blockIdx.y, b = blockIdx.z;
    int c = threadIdx.x;
    int y0 = yq*2;

    const float* wc = w + c*9;
    float w00=wc[0], w01=wc[1], w02=wc[2],
          w10=wc[3], w11=wc[4], w12=wc[5],
          w20=wc[6], w21=wc[7], w22=wc[8];
    float bw = wb[c];

    const ushort* vbase = vbuf + (size_t)b*NN*256 + c;
    auto ldv = [&](int yy, int xx) -> float {
        if ((unsigned)yy >= (unsigned)HH || (unsigned)xx >= (unsigned)WW2) return 0.f;
        return bf2f(vbase[((size_t)yy*WW2 + xx)*256]);
    };

    int x0 = xq*32;
    float rp[4], rc[4];
    #pragma unroll
    for (int r = 0; r < 4; ++r) {
        rp[r] = ldv(y0-1+r, x0-1);
        rc[r] = ldv(y0-1+r, x0);
    }

    #pragma unroll 4
    for (int i = 0; i < 32; ++i) {
        int x = x0 + i;
        float rn[4];
        #pragma unroll
        for (int r = 0; r < 4; ++r) rn[r] = ldv(y0-1+r, x+1);
        #pragma unroll
        for (int o = 0; o < 2; ++o) {
            float conv = bw + w00*rp[o] + w01*rc[o] + w02*rn[o]
                            + w10*rp[o+1] + w11*rc[o+1] + w12*rn[o+1]
                            + w20*rp[o+2] + w21*rc[o+2] + w22*rn[o+2];
            size_t bn = (size_t)b*NN + (size_t)(y0+o)*WW2 + x;
            float qc = bf2f(aq[bn*512 + c]);
            aq[bn*512 + 256 + c] = f2bf(qc*conv);
        }
        #pragma unroll
        for (int r = 0; r < 4; ++r) { rp[r] = rc[r]; rc[r] = rn[r]; }
    }
}

// ------------- MLP dwconv3x3 + skip + exact GELU; 2 ch/thread, 2 rows/block, ring -------------
// grid: dim3(4, 64, 2), 384 threads (ch pairs 0..383 -> channels 2t,2t+1).
__global__ __launch_bounds__(384) void dconv_gelu_row2(const ushort* __restrict__ hdn,
                                                       const float* __restrict__ w,
                                                       const float* __restrict__ bias,
                                                       ushort* __restrict__ out) {
    int xq = blockIdx.x, yq = blockIdx.y, bz = blockIdx.z;
    int c = threadIdx.x * 2;       // channels c, c+1
    int y0 = yq*2;

    float wA[9], wB[9];
    #pragma unroll
    for (int i = 0; i < 9; ++i) { wA[i] = w[c*9 + i]; wB[i] = w[(c+1)*9 + i]; }
    float bw0 = bias[c], bw1 = bias[c+1];

    const ushort* base = hdn + (size_t)bz*NN*HID + c;
    auto ld2 = [&](int yy, int xx) -> float2 {
        if ((unsigned)yy >= (unsigned)HH || (unsigned)xx >= (unsigned)WW2)
            return make_float2(0.f, 0.f);
        ushort2 u = *(const ushort2*)&base[((size_t)yy*WW2 + xx)*HID];
        return make_float2(bf2f(u.x), bf2f(u.y));
    };

    int x0 = xq*32;
    float2 rp[4], rc[4];
    #pragma unroll
    for (int r = 0; r < 4; ++r) {
        rp[r] = ld2(y0-1+r, x0-1);
        rc[r] = ld2(y0-1+r, x0);
    }

    #pragma unroll 4
    for (int i = 0; i < 32; ++i) {
        int x = x0 + i;
        float2 rn[4];
        #pragma unroll
        for (int r = 0; r < 4; ++r) rn[r] = ld2(y0-1+r, x+1);
        #pragma unroll
        for (int o = 0; o < 2; ++o) {
            float conv0 = bw0 + wA[0]*rp[o].x + wA[1]*rc[o].x + wA[2]*rn[o].x
                              + wA[3]*rp[o+1].x + wA[4]*rc[o+1].x + wA[5]*rn[o+1].x
                              + wA[6]*rp[o+2].x + wA[7]*rc[o+2].x + wA[8]*rn[o+2].x;
            float conv1 = bw1 + wB[0]*rp[o].y + wB[1]*rc[o].y + wB[2]*rn[o].y
                              + wB[3]*rp[o+1].y + wB[4]*rc[o+1].y + wB[5]*rn[o+1].y
                              + wB[6]*rp[o+2].y + wB[7]*rc[o+2].y + wB[8]*rn[o+2].y;
            float v0 = rc[o+1].x + conv0;   // center tap = skip
            float v1 = rc[o+1].y + conv1;
            ushort2 res;
            res.x = f2bf(0.5f*v0*(1.f + erff(v0*0.70710678118654752f)));
            res.y = f2bf(0.5f*v1*(1.f + erff(v1*0.70710678118654752f)));
            size_t n = (size_t)bz*NN + (size_t)(y0+o)*WW2 + x;
            *(ushort2*)&out[n*HID + c] = res;
        }
        #pragma unroll
        for (int r = 0; r < 4; ++r) { rp[r] = rc[r]; rc[r] = rn[r]; }
    }
}

extern "C" void kernel_launch(void* const* d_in, const int* in_sizes, int n_in,
                              void* d_out, int out_size, void* d_ws, size_t ws_size,
                              hipStream_t stream) {
    const float* x      = (const float*)d_in[0];
    const float* ln1_g  = (const float*)d_in[3];
    const float* ln1_b  = (const float*)d_in[4];
    const float* qkv_w  = (const float*)d_in[5];
    const float* qkv_b  = (const float*)d_in[6];
    const float* crpe_w = (const float*)d_in[7];
    const float* crpe_b = (const float*)d_in[8];
    const float* proj_w = (const float*)d_in[9];
    const float* proj_b = (const float*)d_in[10];
    const float* ln2_g  = (const float*)d_in[11];
    const float* ln2_b  = (const float*)d_in[12];
    const float* fc1_w  = (const float*)d_in[13];
    const float* fc1_b  = (const float*)d_in[14];
    const float* dconv_w= (const float*)d_in[15];
    const float* dconv_b= (const float*)d_in[16];
    const float* fc2_w  = (const float*)d_in[17];
    const float* fc2_b  = (const float*)d_in[18];
    float* outF = (float*)d_out;
    ushort* ws16 = (ushort*)d_ws;

    // Workspace arena (ushort units) — ~170 MB
    ushort* aq    = ws16;                    // 33,554,432  [B*N,512]: q | gate
    ushort* kbuf  = aq + 33554432;           // 16,777,216
    ushort* vbuf  = kbuf + 16777216;         // 16,777,216
    ushort* sbuf  = vbuf + 16777216;         // 16,777,216  (ln1 out / ln2 out)
    ushort* wqkvT = sbuf + 16777216;         // 196,608
    ushort* wfc1T = wqkvT + 196608;          // 196,608
    ushort* wfc2T = wfc1T + 196608;          // 196,608
    ushort* Bcat  = wfc2T + 196608;          // 524,288  [4][256][512] = WbT | projT
    float*  kvraw = (float*)(Bcat + 524288); // 32,768 f32
    float*  ksumB = kvraw + 32768;           // 1,024 f32
    ushort* hdn   = ws16;                    // alias aq+kbuf: 50,331,648 (after attn done)
    ushort* hdn2  = vbuf;                    // alias vbuf + dead sbuf head: 25,165,824

    const int ROWS = BB*NN;   // 65536

    // ---- weight prep ----
    wtrans<<<dim3(8,24), 256, 0, stream>>>(qkv_w,  wqkvT, CC,  3*CC);
    wtrans<<<dim3(8,24), 256, 0, stream>>>(fc1_w,  wfc1T, CC,  HID);
    wtrans<<<dim3(24,8), 256, 0, stream>>>(fc2_w,  wfc2T, HID, CC);
    wtrans_proj<<<dim3(8,8), 256, 0, stream>>>(proj_w, Bcat);

    // ---- attention branch ----
    ln_bf16v<<<ROWS/4, 256, 0, stream>>>(x, ln1_g, ln1_b, sbuf);
    mfma_gemm<256, 2><<<dim3(6, 512), 256, 0, stream>>>(
        sbuf, wqkvT, qkv_b, nullptr, aq, kbuf, vbuf, 0);
    zero_kernel<<<132, 256, 0, stream>>>(kvraw, 32768 + 1024);
    kv_accum<<<BB*NH*16, 256, 0, stream>>>(kbuf, vbuf, kvraw, ksumB);
    kv_fold<<<32, 256, 0, stream>>>(kvraw, ksumB, proj_w, Bcat);
    attn_gate<<<dim3(4, 64, 4), 256, 0, stream>>>(vbuf, crpe_w, crpe_b, aq);
    // x2 = x + q@Wb + g@proj_w + proj_b  -> d_out (fp32)
    mfma_gemm_attn<<<dim3(2, 128, 4), 256, 0, stream>>>(aq, Bcat, proj_b, x, outF);

    // ---- conv-MLP branch ----
    ln_bf16v<<<ROWS/4, 256, 0, stream>>>(outF, ln2_g, ln2_b, sbuf);
    mfma_gemm<256, 0><<<dim3(6, 512), 256, 0, stream>>>(
        sbuf, wfc1T, fc1_b, nullptr, hdn, nullptr, nullptr, 768);
    for (int p = 0; p < 2; ++p) {
        const ushort* hdn_p = hdn + (size_t)p*2*NN*HID;
        float* xo = outF + (size_t)p*2*NN*CC;
        dconv_gelu_row2<<<dim3(4, 64, 2), 384, 0, stream>>>(hdn_p, dconv_w, dconv_b, hdn2);
        // out = x2 + hdn2 @ fc2_w, in-place on d_out
        mfma_gemm<768, 1><<<dim3(2, 256), 256, 0, stream>>>(
            hdn2, wfc2T, fc2_b, xo, xo, nullptr, nullptr, 256);
    }
}

// Round 14
// 528.006 us; speedup vs baseline: 1.2540x; 1.1020x over previous
//
#include <hip/hip_runtime.h>
#include <math.h>

// Problem constants (setup_inputs is fixed)
#define BB   4
#define HH   128
#define WW2  128
#define NN   (HH*WW2)     // 16384
#define CC   256
#define NH   8
#define HID  768
#define EPSF 1e-6f
#define SCALE 0.17677669529663687f   // 32^-0.5

typedef __attribute__((ext_vector_type(8))) short s8v;   // 8 bf16 (4 VGPRs) MFMA A/B frag
typedef __attribute__((ext_vector_type(4))) float f4v;   // MFMA C/D frag

// ---- bf16 helpers (raw ushort storage) ----
__device__ __forceinline__ float bf2f(ushort h) {
    union { unsigned u; float f; } x; x.u = ((unsigned)h) << 16; return x.f;
}
__device__ __forceinline__ ushort f2bf(float f) {
    union { float f; unsigned u; } x; x.f = f;
    unsigned r = (x.u + 0x7FFFu + ((x.u >> 16) & 1u)) >> 16;
    return (ushort)r;
}

typedef __attribute__((address_space(1))) unsigned gu32;
typedef __attribute__((address_space(3))) unsigned lu32;
__device__ __forceinline__ void gl_lds16(const void* g, void* l) {
    __builtin_amdgcn_global_load_lds((gu32*)g, (lu32*)l, 16, 0, 0);
}

// ---------------- LayerNorm -> bf16, 4 rows per block, vectorized ----------------
__global__ __launch_bounds__(256) void ln_bf16v(const float* __restrict__ in,
                                                const float* __restrict__ g,
                                                const float* __restrict__ bta,
                                                ushort* __restrict__ out) {
    int row  = blockIdx.x*4 + (threadIdx.x >> 6);
    int lane = threadIdx.x & 63;
    const float* p = in + (size_t)row*CC + lane*4;
    float4 v = *(const float4*)p;
    float s  = v.x + v.y + v.z + v.w;
    float s2 = v.x*v.x + v.y*v.y + v.z*v.z + v.w*v.w;
    #pragma unroll
    for (int off = 32; off >= 1; off >>= 1) {
        s  += __shfl_xor(s, off);
        s2 += __shfl_xor(s2, off);
    }
    float mean = s * (1.0f/CC);
    float var  = s2 * (1.0f/CC) - mean*mean;
    float r    = rsqrtf(var + EPSF);
    float4 gv = *(const float4*)&g[lane*4];
    float4 bv = *(const float4*)&bta[lane*4];
    ushort4 o;
    o.x = f2bf((v.x-mean)*r*gv.x + bv.x);
    o.y = f2bf((v.y-mean)*r*gv.y + bv.y);
    o.z = f2bf((v.z-mean)*r*gv.z + bv.z);
    o.w = f2bf((v.w-mean)*r*gv.w + bv.w);
    *(ushort4*)&out[(size_t)row*CC + lane*4] = o;
}

// ---------------- LDS-tiled weight transpose + bf16 cast: w[K][N] -> wt[N][K] ----------------
__global__ __launch_bounds__(256) void wtrans(const float* __restrict__ w,
                                              ushort* __restrict__ wt, int K, int N) {
    __shared__ float tile[32][33];
    int k0 = blockIdx.x*32, n0 = blockIdx.y*32;
    int c = threadIdx.x & 31, r8 = threadIdx.x >> 5;
    #pragma unroll
    for (int r = 0; r < 4; ++r) {
        int kk = r8 + r*8;
        tile[kk][c] = w[(size_t)(k0+kk)*N + n0 + c];
    }
    __syncthreads();
    #pragma unroll
    for (int r = 0; r < 4; ++r) {
        int nn = r8 + r*8;
        wt[(size_t)(n0+nn)*K + k0 + c] = f2bf(tile[c][nn]);
    }
}

// ---- proj_w[K=256][N=256] -> Bcat[b][n][256+k] (projT half of concatenated B), 4 copies ----
__global__ __launch_bounds__(256) void wtrans_proj(const float* __restrict__ w,
                                                   ushort* __restrict__ Bcat) {
    __shared__ float tile[32][33];
    int k0 = blockIdx.x*32, n0 = blockIdx.y*32;
    int c = threadIdx.x & 31, r8 = threadIdx.x >> 5;
    #pragma unroll
    for (int r = 0; r < 4; ++r) {
        int kk = r8 + r*8;
        tile[kk][c] = w[(size_t)(k0+kk)*CC + n0 + c];
    }
    __syncthreads();
    #pragma unroll
    for (int r = 0; r < 4; ++r) {
        int nn = r8 + r*8;
        ushort val = f2bf(tile[c][nn]);
        #pragma unroll
        for (int b = 0; b < BB; ++b)
            Bcat[((size_t)(b*256 + n0+nn))*512 + 256 + k0 + c] = val;
    }
}

// ---------------- bf16 MFMA GEMM: C[M,N] = A[M,K] @ Bt[N,K]^T + bias (+resid) ----------------
// Single-buffer K-loop (16 KB LDS -> max blocks/CU; cross-block overlap hides staging
// latency) + XCD-aware block swizzle + j-inner epilogue (write combine).
// MODE 0: bf16 out, stride NDIM.  MODE 1: f32 out = acc+bias+resid, stride NDIM.
// MODE 2: qkv split writer: col<256 -> aq (stride 512); col<512 -> kbuf; else vbuf (stride 256).
template<int KDIM, int MODE>
__global__ __launch_bounds__(256) void mfma_gemm(const ushort* __restrict__ A,
                                                 const ushort* __restrict__ Bt,
                                                 const float* __restrict__ bias,
                                                 const float* __restrict__ resid,
                                                 void* __restrict__ Cout,
                                                 ushort* __restrict__ kbuf,
                                                 ushort* __restrict__ vbuf,
                                                 int NDIM) {
    __shared__ ushort lsA[128*32];
    __shared__ ushort lsB[128*32];
    int tid  = threadIdx.x;
    int lane = tid & 63;
    int w    = tid >> 6;
    int wm   = w >> 1, wn = w & 1;

    // XCD swizzle: HW block lin -> work swz s.t. work-consecutive blocks (sharing an
    // A-panel) land on the same XCD's contiguous chunk (nwg % 8 == 0).
    int nwg = gridDim.x * gridDim.y;
    int lin = blockIdx.y * gridDim.x + blockIdx.x;
    int swz = (lin & 7) * (nwg >> 3) + (lin >> 3);
    int bx  = swz % gridDim.x;
    int by  = swz / gridDim.x;

    size_t mBase = (size_t)by * 128;
    int    nBase = bx * 128;
    int lrow = lane & 15, lq = lane >> 4;

    const ushort* gA = A  + (mBase + w*32 + (lane>>2))*(size_t)KDIM + (lane&3)*8;
    const ushort* gB = Bt + ((size_t)(nBase + w*32 + (lane>>2)))*(size_t)KDIM + (lane&3)*8;
    ushort* lA = lsA + w*1024;
    ushort* lB = lsB + w*1024;

    f4v acc[4][4] = {};

    for (int k0 = 0; k0 < KDIM; k0 += 32) {
        gl_lds16(gA + k0,           lA);
        gl_lds16(gA + k0 + 16*KDIM, lA + 512);
        gl_lds16(gB + k0,           lB);
        gl_lds16(gB + k0 + 16*KDIM, lB + 512);
        __syncthreads();
        s8v af[4], bfr[4];
        #pragma unroll
        for (int i = 0; i < 4; ++i)
            af[i] = *(const s8v*)&lsA[(wm*64 + i*16 + lrow)*32 + lq*8];
        #pragma unroll
        for (int j = 0; j < 4; ++j)
            bfr[j] = *(const s8v*)&lsB[(wn*64 + j*16 + lrow)*32 + lq*8];
        #pragma unroll
        for (int i = 0; i < 4; ++i)
            #pragma unroll
            for (int j = 0; j < 4; ++j)
                acc[i][j] = __builtin_amdgcn_mfma_f32_16x16x32_bf16(af[i], bfr[j], acc[i][j], 0, 0, 0);
        __syncthreads();
    }

    // Epilogue: j innermost so the 4 column-chunks of each output row issue
    // back-to-back (complete cache lines -> less write amplification).
    int colBase = nBase + wn*64;
    float bs[4];
    #pragma unroll
    for (int j = 0; j < 4; ++j) bs[j] = bias[colBase + j*16 + lrow];
    #pragma unroll
    for (int i = 0; i < 4; ++i) {
        #pragma unroll
        for (int r = 0; r < 4; ++r) {
            size_t row = mBase + wm*64 + i*16 + lq*4 + r;
            #pragma unroll
            for (int j = 0; j < 4; ++j) {
                int col = colBase + j*16 + lrow;
                float v = acc[i][j][r] + bs[j];
                if constexpr (MODE == 0) {
                    ((ushort*)Cout)[row*(size_t)NDIM + col] = f2bf(v);
                } else if constexpr (MODE == 1) {
                    size_t idx = row*(size_t)NDIM + col;
                    ((float*)Cout)[idx] = v + resid[idx];
                } else {
                    if (col < 256)      ((ushort*)Cout)[row*512 + col] = f2bf(v);
                    else if (col < 512) kbuf[row*256 + col - 256] = f2bf(v);
                    else                vbuf[row*256 + col - 512] = f2bf(v);
                }
            }
        }
    }
}

// ---- attention proj GEMM: A=aq[B*N,512] contiguous, B=Bcat per batch, K=512 ----
__global__ __launch_bounds__(256) void mfma_gemm_attn(const ushort* __restrict__ aq,
                                                      const ushort* __restrict__ Bcat,
                                                      const float* __restrict__ bias,
                                                      const float* __restrict__ resid,
                                                      float* __restrict__ Cout) {
    __shared__ ushort lsA[128*32];
    __shared__ ushort lsB[128*32];
    int tid  = threadIdx.x;
    int lane = tid & 63;
    int w    = tid >> 6;
    int wm   = w >> 1, wn = w & 1;
    int b = blockIdx.z;

    // XCD swizzle within the per-batch 2D grid (2*128 = 256 blocks, %8==0).
    int nwg = gridDim.x * gridDim.y;
    int lin = blockIdx.y * gridDim.x + blockIdx.x;
    int swz = (lin & 7) * (nwg >> 3) + (lin >> 3);
    int bx  = swz % gridDim.x;
    int by  = swz / gridDim.x;

    size_t mBase = (size_t)b*NN + (size_t)by * 128;
    int    nBase = bx * 128;
    int lrow = lane & 15, lq = lane >> 4;

    const ushort* gA = aq + (mBase + w*32 + (lane>>2))*512 + (lane&3)*8;
    const ushort* gB = Bcat + ((size_t)(b*256 + nBase + w*32 + (lane>>2)))*512 + (lane&3)*8;
    ushort* lA = lsA + w*1024;
    ushort* lB = lsB + w*1024;

    f4v acc[4][4] = {};

    for (int k0 = 0; k0 < 512; k0 += 32) {
        gl_lds16(gA + k0,          lA);
        gl_lds16(gA + k0 + 16*512, lA + 512);
        gl_lds16(gB + k0,          lB);
        gl_lds16(gB + k0 + 16*512, lB + 512);
        __syncthreads();
        s8v af[4], bfr[4];
        #pragma unroll
        for (int i = 0; i < 4; ++i)
            af[i] = *(const s8v*)&lsA[(wm*64 + i*16 + lrow)*32 + lq*8];
        #pragma unroll
        for (int j = 0; j < 4; ++j)
            bfr[j] = *(const s8v*)&lsB[(wn*64 + j*16 + lrow)*32 + lq*8];
        #pragma unroll
        for (int i = 0; i < 4; ++i)
            #pragma unroll
            for (int j = 0; j < 4; ++j)
                acc[i][j] = __builtin_amdgcn_mfma_f32_16x16x32_bf16(af[i], bfr[j], acc[i][j], 0, 0, 0);
        __syncthreads();
    }

    int colBase = nBase + wn*64;
    float bs[4];
    #pragma unroll
    for (int j = 0; j < 4; ++j) bs[j] = bias[colBase + j*16 + lrow];
    #pragma unroll
    for (int i = 0; i < 4; ++i) {
        #pragma unroll
        for (int r = 0; r < 4; ++r) {
            size_t row = mBase + wm*64 + i*16 + lq*4 + r;
            #pragma unroll
            for (int j = 0; j < 4; ++j) {
                int col = colBase + j*16 + lrow;
                size_t idx = row*(size_t)CC + col;
                Cout[idx] = acc[i][j][r] + bs[j] + resid[idx];
            }
        }
    }
}

__global__ void zero_kernel(float* __restrict__ p, int nElems) {
    int i = blockIdx.x*256 + threadIdx.x;
    if (i < nElems) p[i] = 0.f;
}

// ------------- kv_raw[bh,kd,vd] += sum_n exp(k)*v ; ksum[bh,kd] += sum_n exp(k) -------------
// (no max-shift: |k| <~ 3 so exp() is safe in fp32; softmax is shift-invariant)
__global__ __launch_bounds__(256) void kv_accum(const ushort* __restrict__ kbuf,
                                                const ushort* __restrict__ vbuf,
                                                float* __restrict__ kv_raw,
                                                float* __restrict__ ksum) {
    int blk = blockIdx.x;
    int chunk = blk & 15;
    int bh = blk >> 4;
    int b = bh >> 3, hh = bh & 7;
    int tid = threadIdx.x;
    __shared__ float ke[32][36];
    __shared__ float vv[32][36];
    int tok = tid >> 3;           // 0..31 staging token
    int c4  = (tid & 7) * 4;      // staging channels
    int kd  = tid >> 3;           // compute: fixed k-channel
    int v0  = (tid & 7) * 4;      // compute: 4 v-channels
    float acc0=0.f, acc1=0.f, acc2=0.f, acc3=0.f, ks=0.f;
    for (int it = 0; it < 32; ++it) {
        int nb = chunk*1024 + it*32;
        size_t rowoff = ((size_t)b*NN + nb + tok)*256 + hh*32 + c4;
        ushort4 k4 = *(const ushort4*)&kbuf[rowoff];
        ushort4 v4 = *(const ushort4*)&vbuf[rowoff];
        float4 kf, vf;
        kf.x = expf(bf2f(k4.x)); kf.y = expf(bf2f(k4.y));
        kf.z = expf(bf2f(k4.z)); kf.w = expf(bf2f(k4.w));
        vf.x = bf2f(v4.x); vf.y = bf2f(v4.y); vf.z = bf2f(v4.z); vf.w = bf2f(v4.w);
        *(float4*)&ke[tok][c4] = kf;
        *(float4*)&vv[tok][c4] = vf;
        __syncthreads();
        #pragma unroll
        for (int tt = 0; tt < 32; ++tt) {
            float kval = ke[tt][kd];
            float4 vr = *(const float4*)&vv[tt][v0];
            ks   += kval;
            acc0 += kval*vr.x;
            acc1 += kval*vr.y;
            acc2 += kval*vr.z;
            acc3 += kval*vr.w;
        }
        __syncthreads();
    }
    float* dst = kv_raw + ((size_t)bh*32 + kd)*32 + v0;
    atomicAdd(dst+0, acc0); atomicAdd(dst+1, acc1);
    atomicAdd(dst+2, acc2); atomicAdd(dst+3, acc3);
    if (v0 == 0) atomicAdd(&ksum[bh*32 + kd], ks);
}

// ------------- fold: Bcat[b][j][h*32+kd] = SCALE * sum_vd (kv/ksum)[b,h,kd,vd] * proj_w[h*32+vd][j] -------------
__global__ __launch_bounds__(256) void kv_fold(const float* __restrict__ kv_raw,
                                               const float* __restrict__ ksum,
                                               const float* __restrict__ proj_w,
                                               ushort* __restrict__ Bcat) {
    int bh = blockIdx.x;           // 0..31
    int b = bh >> 3, hh = bh & 7;
    int tid = threadIdx.x;         // j = tid
    __shared__ float kvn[32][33];
    __shared__ float pw[32][256];
    {
        int kd = tid >> 3, v4 = (tid & 7) * 4;
        float inv = 1.0f / ksum[bh*32 + kd];
        const float* src = kv_raw + ((size_t)bh*32 + kd)*32 + v4;
        kvn[kd][v4+0] = src[0]*inv; kvn[kd][v4+1] = src[1]*inv;
        kvn[kd][v4+2] = src[2]*inv; kvn[kd][v4+3] = src[3]*inv;
    }
    for (int vd = 0; vd < 32; ++vd)
        pw[vd][tid] = proj_w[(size_t)(hh*32 + vd)*CC + tid];
    __syncthreads();
    ushort* dst = Bcat + ((size_t)(b*256 + tid))*512 + hh*32;
    for (int kd = 0; kd < 32; ++kd) {
        float acc = 0.f;
        #pragma unroll
        for (int vd = 0; vd < 32; ++vd) acc += kvn[kd][vd] * pw[vd][tid];
        dst[kd] = f2bf(SCALE * acc);
    }
}

// ------------- g = q * (dwconv3x3(v)+bias) -> aq[:,256:512]; 2 rows/block, ring -------------
// grid: (xq=8, yq=64, b=4), 256 threads = channels; x-span 16 (2x blocks for occupancy).
__global__ __launch_bounds__(256) void attn_gate(const ushort* __restrict__ vbuf,
                                                 const float* __restrict__ w,
                                                 const float* __restrict__ wb,
                                                 ushort* __restrict__ aq) {
    int xq = blockIdx.x, yq = blockIdx.y, b = blockIdx.z;
    int c = threadIdx.x;
    int y0 = yq*2;

    const float* wc = w + c*9;
    float w00=wc[0], w01=wc[1], w02=wc[2],
          w10=wc[3], w11=wc[4], w12=wc[5],
          w20=wc[6], w21=wc[7], w22=wc[8];
    float bw = wb[c];

    const ushort* vbase = vbuf + (size_t)b*NN*256 + c;
    auto ldv = [&](int yy, int xx) -> float {
        if ((unsigned)yy >= (unsigned)HH || (unsigned)xx >= (unsigned)WW2) return 0.f;
        return bf2f(vbase[((size_t)yy*WW2 + xx)*256]);
    };

    int x0 = xq*16;
    float rp[4], rc[4];
    #pragma unroll
    for (int r = 0; r < 4; ++r) {
        rp[r] = ldv(y0-1+r, x0-1);
        rc[r] = ldv(y0-1+r, x0);
    }

    #pragma unroll 4
    for (int i = 0; i < 16; ++i) {
        int x = x0 + i;
        float rn[4];
        #pragma unroll
        for (int r = 0; r < 4; ++r) rn[r] = ldv(y0-1+r, x+1);
        #pragma unroll
        for (int o = 0; o < 2; ++o) {
            float conv = bw + w00*rp[o] + w01*rc[o] + w02*rn[o]
                            + w10*rp[o+1] + w11*rc[o+1] + w12*rn[o+1]
                            + w20*rp[o+2] + w21*rc[o+2] + w22*rn[o+2];
            size_t bn = (size_t)b*NN + (size_t)(y0+o)*WW2 + x;
            float qc = bf2f(aq[bn*512 + c]);
            aq[bn*512 + 256 + c] = f2bf(qc*conv);
        }
        #pragma unroll
        for (int r = 0; r < 4; ++r) { rp[r] = rc[r]; rc[r] = rn[r]; }
    }
}

// ------------- MLP dwconv3x3 + skip + exact GELU; 2 ch/thread, 2 rows/block, ring -------------
// grid: dim3(8, 64, 2), 384 threads; x-span 16 (2x blocks: 1024 blocks -> 24 waves/CU cap,
// was 512 blocks -> 12 waves/CU cap which gated occupancy at 27%).
__global__ __launch_bounds__(384) void dconv_gelu_row2(const ushort* __restrict__ hdn,
                                                       const float* __restrict__ w,
                                                       const float* __restrict__ bias,
                                                       ushort* __restrict__ out) {
    int xq = blockIdx.x, yq = blockIdx.y, bz = blockIdx.z;
    int c = threadIdx.x * 2;       // channels c, c+1
    int y0 = yq*2;

    float wA[9], wB[9];
    #pragma unroll
    for (int i = 0; i < 9; ++i) { wA[i] = w[c*9 + i]; wB[i] = w[(c+1)*9 + i]; }
    float bw0 = bias[c], bw1 = bias[c+1];

    const ushort* base = hdn + (size_t)bz*NN*HID + c;
    auto ld2 = [&](int yy, int xx) -> float2 {
        if ((unsigned)yy >= (unsigned)HH || (unsigned)xx >= (unsigned)WW2)
            return make_float2(0.f, 0.f);
        ushort2 u = *(const ushort2*)&base[((size_t)yy*WW2 + xx)*HID];
        return make_float2(bf2f(u.x), bf2f(u.y));
    };

    int x0 = xq*16;
    float2 rp[4], rc[4];
    #pragma unroll
    for (int r = 0; r < 4; ++r) {
        rp[r] = ld2(y0-1+r, x0-1);
        rc[r] = ld2(y0-1+r, x0);
    }

    #pragma unroll 4
    for (int i = 0; i < 16; ++i) {
        int x = x0 + i;
        float2 rn[4];
        #pragma unroll
        for (int r = 0; r < 4; ++r) rn[r] = ld2(y0-1+r, x+1);
        #pragma unroll
        for (int o = 0; o < 2; ++o) {
            float conv0 = bw0 + wA[0]*rp[o].x + wA[1]*rc[o].x + wA[2]*rn[o].x
                              + wA[3]*rp[o+1].x + wA[4]*rc[o+1].x + wA[5]*rn[o+1].x
                              + wA[6]*rp[o+2].x + wA[7]*rc[o+2].x + wA[8]*rn[o+2].x;
            float conv1 = bw1 + wB[0]*rp[o].y + wB[1]*rc[o].y + wB[2]*rn[o].y
                              + wB[3]*rp[o+1].y + wB[4]*rc[o+1].y + wB[5]*rn[o+1].y
                              + wB[6]*rp[o+2].y + wB[7]*rc[o+2].y + wB[8]*rn[o+2].y;
            float v0 = rc[o+1].x + conv0;   // center tap = skip
            float v1 = rc[o+1].y + conv1;
            ushort2 res;
            res.x = f2bf(0.5f*v0*(1.f + erff(v0*0.70710678118654752f)));
            res.y = f2bf(0.5f*v1*(1.f + erff(v1*0.70710678118654752f)));
            size_t n = (size_t)bz*NN + (size_t)(y0+o)*WW2 + x;
            *(ushort2*)&out[n*HID + c] = res;
        }
        #pragma unroll
        for (int r = 0; r < 4; ++r) { rp[r] = rc[r]; rc[r] = rn[r]; }
    }
}

extern "C" void kernel_launch(void* const* d_in, const int* in_sizes, int n_in,
                              void* d_out, int out_size, void* d_ws, size_t ws_size,
                              hipStream_t stream) {
    const float* x      = (const float*)d_in[0];
    const float* ln1_g  = (const float*)d_in[3];
    const float* ln1_b  = (const float*)d_in[4];
    const float* qkv_w  = (const float*)d_in[5];
    const float* qkv_b  = (const float*)d_in[6];
    const float* crpe_w = (const float*)d_in[7];
    const float* crpe_b = (const float*)d_in[8];
    const float* proj_w = (const float*)d_in[9];
    const float* proj_b = (const float*)d_in[10];
    const float* ln2_g  = (const float*)d_in[11];
    const float* ln2_b  = (const float*)d_in[12];
    const float* fc1_w  = (const float*)d_in[13];
    const float* fc1_b  = (const float*)d_in[14];
    const float* dconv_w= (const float*)d_in[15];
    const float* dconv_b= (const float*)d_in[16];
    const float* fc2_w  = (const float*)d_in[17];
    const float* fc2_b  = (const float*)d_in[18];
    float* outF = (float*)d_out;
    ushort* ws16 = (ushort*)d_ws;

    // Workspace arena (ushort units) — ~170 MB
    ushort* aq    = ws16;                    // 33,554,432  [B*N,512]: q | gate
    ushort* kbuf  = aq + 33554432;           // 16,777,216
    ushort* vbuf  = kbuf + 16777216;         // 16,777,216
    ushort* sbuf  = vbuf + 16777216;         // 16,777,216  (ln1 out / ln2 out)
    ushort* wqkvT = sbuf + 16777216;         // 196,608
    ushort* wfc1T = wqkvT + 196608;          // 196,608
    ushort* wfc2T = wfc1T + 196608;          // 196,608
    ushort* Bcat  = wfc2T + 196608;          // 524,288  [4][256][512] = WbT | projT
    float*  kvraw = (float*)(Bcat + 524288); // 32,768 f32
    float*  ksumB = kvraw + 32768;           // 1,024 f32
    ushort* hdn   = ws16;                    // alias aq+kbuf: 50,331,648 (after attn done)
    ushort* hdn2  = vbuf;                    // alias vbuf + dead sbuf head: 25,165,824

    const int ROWS = BB*NN;   // 65536

    // ---- weight prep ----
    wtrans<<<dim3(8,24), 256, 0, stream>>>(qkv_w,  wqkvT, CC,  3*CC);
    wtrans<<<dim3(8,24), 256, 0, stream>>>(fc1_w,  wfc1T, CC,  HID);
    wtrans<<<dim3(24,8), 256, 0, stream>>>(fc2_w,  wfc2T, HID, CC);
    wtrans_proj<<<dim3(8,8), 256, 0, stream>>>(proj_w, Bcat);

    // ---- attention branch ----
    ln_bf16v<<<ROWS/4, 256, 0, stream>>>(x, ln1_g, ln1_b, sbuf);
    mfma_gemm<256, 2><<<dim3(6, 512), 256, 0, stream>>>(
        sbuf, wqkvT, qkv_b, nullptr, aq, kbuf, vbuf, 0);
    zero_kernel<<<132, 256, 0, stream>>>(kvraw, 32768 + 1024);
    kv_accum<<<BB*NH*16, 256, 0, stream>>>(kbuf, vbuf, kvraw, ksumB);
    kv_fold<<<32, 256, 0, stream>>>(kvraw, ksumB, proj_w, Bcat);
    attn_gate<<<dim3(8, 64, 4), 256, 0, stream>>>(vbuf, crpe_w, crpe_b, aq);
    // x2 = x + q@Wb + g@proj_w + proj_b  -> d_out (fp32)
    mfma_gemm_attn<<<dim3(2, 128, 4), 256, 0, stream>>>(aq, Bcat, proj_b, x, outF);

    // ---- conv-MLP branch ----
    ln_bf16v<<<ROWS/4, 256, 0, stream>>>(outF, ln2_g, ln2_b, sbuf);
    mfma_gemm<256, 0><<<dim3(6, 512), 256, 0, stream>>>(
        sbuf, wfc1T, fc1_b, nullptr, hdn, nullptr, nullptr, 768);
    for (int p = 0; p < 2; ++p) {
        const ushort* hdn_p = hdn + (size_t)p*2*NN*HID;
        float* xo = outF + (size_t)p*2*NN*CC;
        dconv_gelu_row2<<<dim3(8, 64, 2), 384, 0, stream>>>(hdn_p, dconv_w, dconv_b, hdn2);
        // out = x2 + hdn2 @ fc2_w, in-place on d_out
        mfma_gemm<768, 1><<<dim3(2, 256), 256, 0, stream>>>(
            hdn2, wfc2T, fc2_b, xo, xo, nullptr, nullptr, 256);
    }
}